// Round 1
// baseline (230.122 us; speedup 1.0000x reference)
//
#include <hip/hip_runtime.h>

// CrossWinAttention on MI355X (gfx950), bf16 MFMA pipeline.
// R1 design:
//  - mean-over-N folded BEFORE final projection (linearity) -> 6x less final GEMM
//  - LN gamma/beta folded into transposed bf16 weights/biases (k_prep)
//  - softmax scale * log2(e) folded into wq/bq -> exp == single v_exp_f32 (2^x),
//    no max subtraction (scores bounded, softmax shift-invariant)
//  - ws layout: wqT/wkT/wvT/wpT bf16 | bq'/bk'/bv' f32 | qh/kh/vh bf16 [bl][h][384][32] | abar bf16 [8192][128]
//    total ~40 MB

typedef unsigned short u16;
typedef __bf16 bf16x8 __attribute__((ext_vector_type(8)));
typedef float  f32x16 __attribute__((ext_vector_type(16)));
typedef unsigned short u16x8 __attribute__((ext_vector_type(8)));

__device__ __forceinline__ u16 f2bf(float f){
  unsigned u = __float_as_uint(f);
  u += 0x7fffu + ((u >> 16) & 1u);   // RNE
  return (u16)(u >> 16);
}

__device__ __forceinline__ f32x16 mfma_bf16(bf16x8 a, bf16x8 b, f32x16 c){
  return __builtin_amdgcn_mfma_f32_32x32x16_bf16(a, b, c, 0, 0, 0);
}

// Fragment conventions (32x32x16 bf16):
//  A: m = lane&31, k = (lane>>5)*8 + j   (j = 0..7, contiguous in memory)
//  B: n = lane&31, k = (lane>>5)*8 + j
//  C/D: col = lane&31, row = (reg&3) + 8*(reg>>2) + 4*(lane>>5)   [verified m74/m101]
// A/B share the k-slot mapping, so any k-permutation error cancels in the contraction.

// ---------------------------------------------------------------- k_prep
// 16 blocks x 128 thr. blockIdx>>2 selects {wq,wk,wv,wp}; &3 selects n-quarter.
// wT[n][k] = w[k][n] * g[k] * alpha ; bias'[n] = (b[n] + sum_k beta[k] w[k][n]) * alpha
__global__ __launch_bounds__(128) void k_prep(
    const float* __restrict__ wq, const float* __restrict__ bq,
    const float* __restrict__ gq, const float* __restrict__ betq,
    const float* __restrict__ wk, const float* __restrict__ bk,
    const float* __restrict__ gk, const float* __restrict__ betk,
    const float* __restrict__ wv, const float* __restrict__ bv,
    const float* __restrict__ gv, const float* __restrict__ betv,
    const float* __restrict__ wp,
    u16* __restrict__ wqT, u16* __restrict__ wkT, u16* __restrict__ wvT, u16* __restrict__ wpT,
    float* __restrict__ bq2, float* __restrict__ bk2, float* __restrict__ bv2)
{
  const float ALPHA_Q = 0.17677669529663687f * 1.4426950408889634f; // DH^-0.5 * log2(e)
  int wsel = blockIdx.x >> 2, qq = blockIdx.x & 3;
  int tid = threadIdx.x;  // = input channel k
  const float *w, *bb, *g, *bet; u16* wT; float* b2; float alpha;
  if (wsel == 0){ w=wq; bb=bq; g=gq; bet=betq; wT=wqT; b2=bq2; alpha=ALPHA_Q; }
  else if (wsel == 1){ w=wk; bb=bk; g=gk; bet=betk; wT=wkT; b2=bk2; alpha=1.f; }
  else if (wsel == 2){ w=wv; bb=bv; g=gv; bet=betv; wT=wvT; b2=bv2; alpha=1.f; }
  else { w=wp; bb=nullptr; g=nullptr; bet=nullptr; wT=wpT; b2=nullptr; alpha=1.f; }
  float sc = (g ? g[tid] : 1.f) * alpha;
  for (int nn = 0; nn < 32; nn++){
    int n = qq*32 + nn;
    wT[n*128 + tid] = f2bf(w[tid*128 + n] * sc);   // coalesced writes, cached strided reads
  }
  if (qq == 0 && bb){
    float s = bb[tid];                              // n = tid
    for (int k2 = 0; k2 < 128; k2++) s += bet[k2] * w[k2*128 + tid];
    b2[tid] = s * alpha;
  }
}

// ---------------------------------------------------------------- k_lnproj
// grid 2304 = 128 (b,l) * 6 (n chunk) * 3 (q/k/v); 256 thr (4 waves).
// 64 tokens (one n, contiguous 32KB) : LN -> bf16 -> (64x128)@(128x128) MFMA -> ws.
__global__ __launch_bounds__(256) void k_lnproj(
    const float* __restrict__ qg, const float* __restrict__ kg, const float* __restrict__ vg,
    const u16* __restrict__ wqT, const u16* __restrict__ wkT, const u16* __restrict__ wvT,
    const float* __restrict__ bq2, const float* __restrict__ bk2, const float* __restrict__ bv2,
    u16* __restrict__ qh, u16* __restrict__ kh, u16* __restrict__ vh)
{
  __shared__ alignas(16) float Af[64*132];   // +4 pad: stats reads conflict-free
  __shared__ float mean_s[64], rstd_s[64];
  __shared__ alignas(16) u16 Abf[64*136];    // stride 136: 16B-aligned rows (4-way ok)
  int bid = blockIdx.x, tid = threadIdx.x;
  int which = bid % 3;
  int t = bid / 3;
  int n = t % 6, bl = t / 6;
  const float* src; const u16* wT; const float* b2; u16* dstb;
  if (which == 0){ src=qg; wT=wqT; b2=bq2; dstb=qh; }
  else if (which == 1){ src=kg; wT=wkT; b2=bk2; dstb=kh; }
  else { src=vg; wT=wvT; b2=bv2; dstb=vh; }
  int b = bl >> 6, l = bl & 63;
  const float4* s4 = (const float4*)(src + (size_t)((b*6 + n)*64 + l)*64*128);
  #pragma unroll
  for (int i = 0; i < 8; i++){
    int idx = tid + i*256;
    int row = idx >> 5, c4 = idx & 31;
    *(float4*)&Af[row*132 + c4*4] = s4[row*32 + c4];
  }
  __syncthreads();
  if (tid < 64){
    float s = 0.f, s2 = 0.f;
    for (int i = 0; i < 128; i++){
      int d = ((tid & 31) + i) & 127;      // rotated start: 2 lanes/bank (free)
      float x = Af[tid*132 + d];
      s += x; s2 += x*x;
    }
    float m = s * (1.f/128.f);
    mean_s[tid] = m;
    rstd_s[tid] = rsqrtf(s2*(1.f/128.f) - m*m + 1e-5f);
  }
  __syncthreads();
  #pragma unroll
  for (int i = 0; i < 32; i++){
    int idx = tid + i*256;
    int row = idx >> 7, d = idx & 127;
    Abf[row*136 + d] = f2bf((Af[row*132 + d] - mean_s[row]) * rstd_s[row]);
  }
  __syncthreads();
  int wave = tid >> 6, lane = tid & 63, lm = lane & 31, lh = lane >> 5;
  // B-fragments straight from global wT (L2-resident, reused by all 2304 blocks)
  bf16x8 bfr[8];
  const u16* wrow = wT + (32*wave + lm)*128 + lh*8;
  #pragma unroll
  for (int ks = 0; ks < 8; ks++) bfr[ks] = *(const bf16x8*)(wrow + ks*16);
  f32x16 acc0, acc1;
  #pragma unroll
  for (int r = 0; r < 16; r++){ acc0[r]=0.f; acc1[r]=0.f; }
  #pragma unroll
  for (int ks = 0; ks < 8; ks++){
    bf16x8 a0 = *(const bf16x8*)&Abf[lm*136       + ks*16 + lh*8];
    bf16x8 a1 = *(const bf16x8*)&Abf[(32+lm)*136  + ks*16 + lh*8];
    acc0 = mfma_bf16(a0, bfr[ks], acc0);
    acc1 = mfma_bf16(a1, bfr[ks], acc1);
  }
  // wave w == head w (cols 32w..32w+31); dh = lm
  float bias = b2[32*wave + lm];
  u16* dst = dstb + ((size_t)(bl*4 + wave)*384 + n*64)*32 + lm;
  #pragma unroll
  for (int r = 0; r < 16; r++){
    int row0 = (r&3) + 8*(r>>2) + 4*lh;
    dst[(size_t)row0*32]      = f2bf(acc0[r] + bias);
    dst[(size_t)(32+row0)*32] = f2bf(acc1[r] + bias);
  }
}

// ---------------------------------------------------------------- k_attn
// grid 512 = 128 (b,l) * 4 heads; 384 thr (6 waves; wave w == n=w's 64 q rows).
// No-max softmax (scores already in log2 domain), P via per-wave LDS round-trip,
// mean over n reduced in-block into abar_s. LDS 48.6 KB (<64 KB static limit).
__global__ __launch_bounds__(384) void k_attn(
    const u16* __restrict__ qh, const u16* __restrict__ kh, const u16* __restrict__ vh,
    u16* __restrict__ abar)
{
  __shared__ alignas(16) u16 vts[32*392];   // V^T [dh][key], pad->392 (16B rows)
  __shared__ alignas(16) u16 ps[6*32*40];   // per-wave P tile [32 rows][32 keys], stride 40
  __shared__ float abar_s[64*32];
  int bid = blockIdx.x, tid = threadIdx.x;
  int h = bid & 3, bl = bid >> 2;
  const u16* qb = qh + (size_t)bid * (384*32);
  const u16* kb = kh + (size_t)bid * (384*32);
  const u16* vb = vh + (size_t)bid * (384*32);

  // stage V transposed
  #pragma unroll
  for (int i = 0; i < 4; i++){
    int c = tid + i*384;           // 1536 16B chunks
    int row = c >> 2, part = c & 3;
    u16x8 vv = *(const u16x8*)(vb + row*32 + part*8);
    #pragma unroll
    for (int j = 0; j < 8; j++) vts[(part*8 + j)*392 + row] = vv[j];
  }
  for (int idx = tid; idx < 2048; idx += 384) abar_s[idx] = 0.f;
  __syncthreads();

  int wave = tid >> 6, lane = tid & 63, lm = lane & 31, lh = lane >> 5;
  u16* pw = &ps[wave * (32*40)];

  bf16x8 qf[2][2];   // q rows wave*64 + rt*32 + lm, reused across all 12 key tiles
  #pragma unroll
  for (int rt = 0; rt < 2; rt++)
    #pragma unroll
    for (int ks = 0; ks < 2; ks++)
      qf[rt][ks] = *(const bf16x8*)(qb + (wave*64 + rt*32 + lm)*32 + ks*16 + lh*8);

  f32x16 oacc[2];
  float lsum[32];
  #pragma unroll
  for (int r = 0; r < 16; r++){ oacc[0][r] = 0.f; oacc[1][r] = 0.f; }
  #pragma unroll
  for (int r = 0; r < 32; r++) lsum[r] = 0.f;

  for (int kt = 0; kt < 12; kt++){
    int K0 = kt*32;
    // K B-fragments from global (this block's 24KB slice stays L1/L2-hot)
    bf16x8 kf0 = *(const bf16x8*)(kb + (K0+lm)*32 +      lh*8);
    bf16x8 kf1 = *(const bf16x8*)(kb + (K0+lm)*32 + 16 + lh*8);
    bf16x8 vf0 = *(const bf16x8*)&vts[lm*392 + K0 +      lh*8];
    bf16x8 vf1 = *(const bf16x8*)&vts[lm*392 + K0 + 16 + lh*8];
    #pragma unroll
    for (int rt = 0; rt < 2; rt++){
      f32x16 s;
      #pragma unroll
      for (int r = 0; r < 16; r++) s[r] = 0.f;
      s = mfma_bf16(qf[rt][0], kf0, s);
      s = mfma_bf16(qf[rt][1], kf1, s);
      #pragma unroll
      for (int r = 0; r < 16; r++){
        float e = exp2f(s[r]);                 // scale*log2e pre-folded into wq/bq
        lsum[rt*16 + r] += e;
        pw[((r&3) + 8*(r>>2) + 4*lh)*40 + lm] = f2bf(e);  // C-layout -> [row][key]
      }
      bf16x8 pf0 = *(const bf16x8*)&pw[lm*40 +      lh*8];
      bf16x8 pf1 = *(const bf16x8*)&pw[lm*40 + 16 + lh*8];
      oacc[rt] = mfma_bf16(pf0, vf0, oacc[rt]);
      oacc[rt] = mfma_bf16(pf1, vf1, oacc[rt]);
    }
  }

  // row sums: reduce lsum across the 32-lane col groups, scale O, 1/6 mean fold
  #pragma unroll
  for (int rt = 0; rt < 2; rt++){
    #pragma unroll
    for (int r = 0; r < 16; r++){
      float sle = lsum[rt*16 + r];
      #pragma unroll
      for (int m = 1; m < 32; m <<= 1) sle += __shfl_xor(sle, m, 64);
      float o = oacc[rt][r] * ((1.f/6.f) / sle);
      int row0 = (r&3) + 8*(r>>2) + 4*lh;      // w1w2 = rt*32 + row0 (since n == wave)
      atomicAdd(&abar_s[(rt*32 + row0)*32 + lm], o);
    }
  }
  __syncthreads();
  u16* ob = abar + (size_t)(bl*64)*128 + h*32;
  for (int idx = tid; idx < 2048; idx += 384){
    int w12 = idx >> 5, dh = idx & 31;
    ob[(size_t)w12*128 + dh] = f2bf(abar_s[idx]);
  }
}

// ---------------------------------------------------------------- k_out
// grid 128 x 256 thr: out[8192][128] = abar @ wpT + bp + skip (fp32 out).
__global__ __launch_bounds__(256) void k_out(
    const u16* __restrict__ abar, const u16* __restrict__ wpT,
    const float* __restrict__ bp, const float* __restrict__ skip,
    float* __restrict__ out)
{
  __shared__ alignas(16) u16 Als[64*136];
  int tid = threadIdx.x;
  int R0 = blockIdx.x * 64;
  #pragma unroll
  for (int i = 0; i < 4; i++){
    int c = tid + i*256;           // 1024 16B chunks
    int row = c >> 4, part = c & 15;
    *(u16x8*)&Als[row*136 + part*8] = *(const u16x8*)(abar + (size_t)(R0+row)*128 + part*8);
  }
  __syncthreads();
  int wave = tid >> 6, lane = tid & 63, lm = lane & 31, lh = lane >> 5;
  bf16x8 bfr[8];
  const u16* wrow = wpT + (32*wave + lm)*128 + lh*8;
  #pragma unroll
  for (int ks = 0; ks < 8; ks++) bfr[ks] = *(const bf16x8*)(wrow + ks*16);
  f32x16 acc0, acc1;
  #pragma unroll
  for (int r = 0; r < 16; r++){ acc0[r]=0.f; acc1[r]=0.f; }
  #pragma unroll
  for (int ks = 0; ks < 8; ks++){
    bf16x8 a0 = *(const bf16x8*)&Als[lm*136      + ks*16 + lh*8];
    bf16x8 a1 = *(const bf16x8*)&Als[(32+lm)*136 + ks*16 + lh*8];
    acc0 = mfma_bf16(a0, bfr[ks], acc0);
    acc1 = mfma_bf16(a1, bfr[ks], acc1);
  }
  float bias = bp[32*wave + lm];
  #pragma unroll
  for (int r = 0; r < 16; r++){
    int row0 = (r&3) + 8*(r>>2) + 4*lh;
    size_t f0 = (size_t)(R0 + row0)*128 + 32*wave + lm;
    out[f0] = acc0[r] + bias + skip[f0];
    size_t f1 = (size_t)(R0 + 32 + row0)*128 + 32*wave + lm;
    out[f1] = acc1[r] + bias + skip[f1];
  }
}

// ---------------------------------------------------------------- launch
extern "C" void kernel_launch(void* const* d_in, const int* in_sizes, int n_in,
                              void* d_out, int out_size, void* d_ws, size_t ws_size,
                              hipStream_t stream)
{
  const float* q    = (const float*)d_in[0];
  const float* k    = (const float*)d_in[1];
  const float* v    = (const float*)d_in[2];
  const float* skip = (const float*)d_in[3];
  const float* gq   = (const float*)d_in[4];
  const float* betq = (const float*)d_in[5];
  const float* gk   = (const float*)d_in[6];
  const float* betk = (const float*)d_in[7];
  const float* gv   = (const float*)d_in[8];
  const float* betv = (const float*)d_in[9];
  const float* wq   = (const float*)d_in[10];
  const float* bq   = (const float*)d_in[11];
  const float* wk   = (const float*)d_in[12];
  const float* bk   = (const float*)d_in[13];
  const float* wv   = (const float*)d_in[14];
  const float* bv   = (const float*)d_in[15];
  const float* wp   = (const float*)d_in[16];
  const float* bp   = (const float*)d_in[17];
  float* out = (float*)d_out;

  char* ws = (char*)d_ws;
  u16* wqT = (u16*)ws;                 // 16384 elems each
  u16* wkT = wqT + 16384;
  u16* wvT = wkT + 16384;
  u16* wpT = wvT + 16384;
  float* bq2 = (float*)(ws + 131072);  // 128 f32 each
  float* bk2 = bq2 + 128;
  float* bv2 = bk2 + 128;
  u16* qh = (u16*)(ws + 132608);       // [128][4][384][32] bf16 = 12.6 MB each
  u16* kh = qh + 6291456;
  u16* vh = kh + 6291456;
  u16* abar = vh + 6291456;            // [8192][128] bf16 = 2 MB
  // total ws use: 39,978,496 B

  k_prep  <<<16,   128, 0, stream>>>(wq,bq,gq,betq, wk,bk,gk,betk, wv,bv,gv,betv, wp,
                                     wqT,wkT,wvT,wpT, bq2,bk2,bv2);
  k_lnproj<<<2304, 256, 0, stream>>>(q,k,v, wqT,wkT,wvT, bq2,bk2,bv2, qh,kh,vh);
  k_attn  <<<512,  384, 0, stream>>>(qh,kh,vh, abar);
  k_out   <<<128,  256, 0, stream>>>(abar, wpT, bp, skip, out);
}

// Round 2
// 224.185 us; speedup vs baseline: 1.0265x; 1.0265x over previous
//
#include <hip/hip_runtime.h>

// CrossWinAttention on MI355X (gfx950), bf16 MFMA pipeline. R2:
//  - k_attn: S^T = K*Q^T so P stays in registers (C-layout == PV A-layout per
//    key-group); V^T staged in LDS with matching key swizzle -> single 16B
//    B-fragment reads. No P LDS round-trip, 2 barriers total, 768 thr/block,
//    LDS 34 KB -> 2 blocks/CU = 24 waves/CU.
//  - k_lnproj: LN folded into GEMM epilogue: y = r*(x@W') - r*m*u + b'.
//    GEMM on raw bf16 x; stats via in-flight shuffle reduction. No fp32 LDS
//    stage, no serial stats loop.
//  - mean-over-N folded before final projection (linearity).
//  - softmax scale*log2(e) folded into wq/bq -> exp2 only, no max subtraction.

typedef unsigned short u16;
typedef __bf16 bf16x8 __attribute__((ext_vector_type(8)));
typedef float  f32x16 __attribute__((ext_vector_type(16)));
typedef unsigned short u16x8 __attribute__((ext_vector_type(8)));
typedef unsigned short u16x4 __attribute__((ext_vector_type(4)));

union U8 { u16x8 u; bf16x8 b; };

__device__ __forceinline__ u16 f2bf(float f){
  unsigned u = __float_as_uint(f);
  u += 0x7fffu + ((u >> 16) & 1u);   // RNE
  return (u16)(u >> 16);
}

__device__ __forceinline__ f32x16 mfma_bf16(bf16x8 a, bf16x8 b, f32x16 c){
  return __builtin_amdgcn_mfma_f32_32x32x16_bf16(a, b, c, 0, 0, 0);
}

// 32x32x16 bf16 fragment conventions:
//  A: m=lane&31, k=(lane>>5)*8+j ; B: n=lane&31, k=(lane>>5)*8+j
//  C/D: col=lane&31, row=(reg&3)+8*(reg>>2)+4*(lane>>5)   [verified m74/m101]
// S^T = mfma(K, Q): col = q = lane&31 (fixed!), reg axis = keys:
//   reg r -> key K0 + (r&3)+8*(r>>2)+4*lh
// => regs 0..7 are exactly PV A-slots (lh,j) for keys 4lh+{0,1,2,3,8,9,10,11},
//    regs 8..15 for +16. V^T stored with the same key swizzle makes the PV
//    B-fragment one contiguous 16B read. A/B share slot pairing, so any common
//    k-permutation cancels in the contraction.

// ---------------------------------------------------------------- k_prep
__global__ __launch_bounds__(128) void k_prep(
    const float* __restrict__ wq, const float* __restrict__ bq,
    const float* __restrict__ gq, const float* __restrict__ betq,
    const float* __restrict__ wk, const float* __restrict__ bk,
    const float* __restrict__ gk, const float* __restrict__ betk,
    const float* __restrict__ wv, const float* __restrict__ bv,
    const float* __restrict__ gv, const float* __restrict__ betv,
    const float* __restrict__ wp,
    u16* __restrict__ wqT, u16* __restrict__ wkT, u16* __restrict__ wvT, u16* __restrict__ wpT,
    float* __restrict__ bq2, float* __restrict__ bk2, float* __restrict__ bv2,
    float* __restrict__ uq2, float* __restrict__ uk2, float* __restrict__ uv2)
{
  const float ALPHA_Q = 0.17677669529663687f * 1.4426950408889634f; // DH^-0.5 * log2(e)
  int wsel = blockIdx.x >> 2, qq = blockIdx.x & 3;
  int tid = threadIdx.x;  // = input channel k
  const float *w, *bb, *g, *bet; u16* wT; float *b2, *u2; float alpha;
  if (wsel == 0){ w=wq; bb=bq; g=gq; bet=betq; wT=wqT; b2=bq2; u2=uq2; alpha=ALPHA_Q; }
  else if (wsel == 1){ w=wk; bb=bk; g=gk; bet=betk; wT=wkT; b2=bk2; u2=uk2; alpha=1.f; }
  else if (wsel == 2){ w=wv; bb=bv; g=gv; bet=betv; wT=wvT; b2=bv2; u2=uv2; alpha=1.f; }
  else { w=wp; bb=nullptr; g=nullptr; bet=nullptr; wT=wpT; b2=nullptr; u2=nullptr; alpha=1.f; }
  float sc = (g ? g[tid] : 1.f) * alpha;
  for (int nn = 0; nn < 32; nn++){
    int n = qq*32 + nn;
    wT[n*128 + tid] = f2bf(w[tid*128 + n] * sc);
  }
  if (qq == 0 && bb){
    float s = bb[tid], su = 0.f;                    // n = tid
    for (int k2 = 0; k2 < 128; k2++){
      float wv_ = w[k2*128 + tid];
      s  += bet[k2] * wv_;
      su += g[k2] * wv_;
    }
    b2[tid] = s * alpha;
    u2[tid] = su * alpha;
  }
}

// ---------------------------------------------------------------- k_lnproj
// grid 2304 = 128 (b,l) * 6 (n) * 3 (q/k/v); 256 thr (4 waves).
// Raw-x bf16 GEMM; LN applied in epilogue: y = r*z - r*m*u2[n] + b2[n].
__global__ __launch_bounds__(256) void k_lnproj(
    const float* __restrict__ qg, const float* __restrict__ kg, const float* __restrict__ vg,
    const u16* __restrict__ wqT, const u16* __restrict__ wkT, const u16* __restrict__ wvT,
    const float* __restrict__ bq2, const float* __restrict__ bk2, const float* __restrict__ bv2,
    const float* __restrict__ uq2, const float* __restrict__ uk2, const float* __restrict__ uv2,
    u16* __restrict__ qh, u16* __restrict__ kh, u16* __restrict__ vh)
{
  __shared__ alignas(16) u16 Abf[64*136];
  __shared__ float s1s[64], s2s[64];     // reused as rs / rm after barrier1
  int bid = blockIdx.x, tid = threadIdx.x;
  int which = bid % 3;
  int t = bid / 3;
  int n = t % 6, bl = t / 6;
  const float* src; const u16* wT; const float *b2, *u2; u16* dstb;
  if (which == 0){ src=qg; wT=wqT; b2=bq2; u2=uq2; dstb=qh; }
  else if (which == 1){ src=kg; wT=wkT; b2=bk2; u2=uk2; dstb=kh; }
  else { src=vg; wT=wvT; b2=bv2; u2=uv2; dstb=vh; }
  int b = bl >> 6, l = bl & 63;
  const float4* s4 = (const float4*)(src + (size_t)((b*6 + n)*64 + l)*64*128);
  #pragma unroll
  for (int i = 0; i < 8; i++){
    int idx = tid + i*256;
    int row = idx >> 5, c4 = idx & 31;
    float4 xv = s4[idx];
    float s1 = xv.x + xv.y + xv.z + xv.w;
    float s2 = xv.x*xv.x + xv.y*xv.y + xv.z*xv.z + xv.w*xv.w;
    #pragma unroll
    for (int m = 1; m < 32; m <<= 1){
      s1 += __shfl_xor(s1, m, 64);
      s2 += __shfl_xor(s2, m, 64);
    }
    if (c4 == 0){ s1s[row] = s1; s2s[row] = s2; }
    u16x4 pk = { f2bf(xv.x), f2bf(xv.y), f2bf(xv.z), f2bf(xv.w) };
    *(u16x4*)&Abf[row*136 + c4*4] = pk;
  }
  __syncthreads();
  if (tid < 64){
    float m = s1s[tid] * (1.f/128.f);
    float r = rsqrtf(s2s[tid] * (1.f/128.f) - m*m + 1e-5f);
    s1s[tid] = r;          // rs
    s2s[tid] = r * m;      // rm
  }
  int wave = tid >> 6, lane = tid & 63, lm = lane & 31, lh = lane >> 5;
  bf16x8 bfr[8];
  const u16* wrow = wT + (32*wave + lm)*128 + lh*8;
  #pragma unroll
  for (int ks = 0; ks < 8; ks++) bfr[ks] = *(const bf16x8*)(wrow + ks*16);
  f32x16 acc0, acc1;
  #pragma unroll
  for (int r = 0; r < 16; r++){ acc0[r]=0.f; acc1[r]=0.f; }
  #pragma unroll
  for (int ks = 0; ks < 8; ks++){
    bf16x8 a0 = *(const bf16x8*)&Abf[lm*136       + ks*16 + lh*8];
    bf16x8 a1 = *(const bf16x8*)&Abf[(32+lm)*136  + ks*16 + lh*8];
    acc0 = mfma_bf16(a0, bfr[ks], acc0);
    acc1 = mfma_bf16(a1, bfr[ks], acc1);
  }
  __syncthreads();   // rs/rm ready (cheap: all waves exit MFMA together)
  int col = 32*wave + lm;
  float u2c = u2[col], bc = b2[col];
  u16* dst = dstb + ((size_t)(bl*4 + wave)*384 + n*64)*32 + lm;
  #pragma unroll
  for (int r = 0; r < 16; r++){
    int row0 = (r&3) + 8*(r>>2) + 4*lh;
    float y0 = s1s[row0]     * acc0[r] - s2s[row0]     * u2c + bc;
    float y1 = s1s[row0+32]  * acc1[r] - s2s[row0+32]  * u2c + bc;
    dst[(size_t)row0*32]      = f2bf(y0);
    dst[(size_t)(32+row0)*32] = f2bf(y1);
  }
}

// ---------------------------------------------------------------- k_attn
// grid 512 = (b,l)*h; 768 thr = 12 waves; wave w: n = w>>1, q-half = w&1.
// S^T trick keeps P in registers; V^T in LDS, key-swizzled. LDS 34.3 KB.
__global__ __launch_bounds__(768, 6) void k_attn(
    const u16* __restrict__ qh, const u16* __restrict__ kh, const u16* __restrict__ vh,
    u16* __restrict__ abar)
{
  __shared__ alignas(16) u16 vts[32*408];   // V^T [dh][swizzled key], stride 408
  __shared__ float abar_s[64*32];
  int bid = blockIdx.x, tid = threadIdx.x;
  int h = bid & 3, bl = bid >> 2;
  const u16* qb = qh + (size_t)bid * (384*32);
  const u16* kb = kh + (size_t)bid * (384*32);
  const u16* vb = vh + (size_t)bid * (384*32);

  // stage V transposed + key-swizzled: key u (mod 32) at a-group perm{0,2,1,3,4,6,5,7}
  #pragma unroll
  for (int i = 0; i < 2; i++){
    int c = tid + i*768;               // 1536 16B chunks
    int key = c >> 2, part = c & 3;
    int u = key & 31, tt = key >> 5;
    int a = u >> 2;
    int anew = (a & 4) | ((a & 1) << 1) | ((a >> 1) & 1);
    int pos = tt*32 + anew*4 + (u & 3);
    u16x8 vv = *(const u16x8*)(vb + key*32 + part*8);
    #pragma unroll
    for (int j = 0; j < 8; j++) vts[(part*8 + j)*408 + pos] = vv[j];
  }
  for (int idx = tid; idx < 2048; idx += 768) abar_s[idx] = 0.f;
  __syncthreads();

  int wave = tid >> 6, lane = tid & 63, lm = lane & 31, lh = lane >> 5;
  int n = wave >> 1, qoff = (wave & 1) * 32;
  int qrow = n*64 + qoff + lm;

  bf16x8 qf0 = *(const bf16x8*)(qb + qrow*32 +      lh*8);
  bf16x8 qf1 = *(const bf16x8*)(qb + qrow*32 + 16 + lh*8);

  f32x16 oacc;
  #pragma unroll
  for (int r = 0; r < 16; r++) oacc[r] = 0.f;
  float sle = 0.f;

  const u16* vrow = &vts[lm*408 + 8*lh];

  for (int kt = 0; kt < 12; kt++){
    int K0 = kt*32;
    bf16x8 kf0 = *(const bf16x8*)(kb + (K0+lm)*32 +      lh*8);
    bf16x8 kf1 = *(const bf16x8*)(kb + (K0+lm)*32 + 16 + lh*8);
    f32x16 s;
    #pragma unroll
    for (int r = 0; r < 16; r++) s[r] = 0.f;
    s = mfma_bf16(kf0, qf0, s);        // S^T: col = q = lm, regs = keys
    s = mfma_bf16(kf1, qf1, s);
    U8 p0, p1;
    #pragma unroll
    for (int r = 0; r < 8; r++){
      float e0 = exp2f(s[r]);
      float e1 = exp2f(s[r+8]);
      sle += e0 + e1;
      p0.u[r] = f2bf(e0);
      p1.u[r] = f2bf(e1);
    }
    U8 vb0, vb1;
    vb0.u = *(const u16x8*)(vrow + K0);       // keys 4lh+{0-3,8-11} (swizzled)
    vb1.u = *(const u16x8*)(vrow + K0 + 16);  // keys 16+4lh+{0-3,8-11}
    oacc = mfma_bf16(p0.b, vb0.b, oacc);
    oacc = mfma_bf16(p1.b, vb1.b, oacc);
  }

  // total row sum for q = lm: combine lh halves
  sle += __shfl_xor(sle, 32, 64);

  // oacc lane(lm,lh) reg r = O[q = qoff+(r&3)+8*(r>>2)+4*lh][dh = lm]
  #pragma unroll
  for (int r = 0; r < 16; r++){
    int q_l = (r&3) + 8*(r>>2) + 4*lh;
    float norm = __shfl(sle, q_l, 64);
    float o = oacc[r] * ((1.f/6.f) / norm);
    atomicAdd(&abar_s[(qoff + q_l)*32 + lm], o);
  }
  __syncthreads();
  u16* ob = abar + (size_t)(bl*64)*128 + h*32;
  for (int idx = tid; idx < 2048; idx += 768){
    int w12 = idx >> 5, dh = idx & 31;
    ob[(size_t)w12*128 + dh] = f2bf(abar_s[idx]);
  }
}

// ---------------------------------------------------------------- k_out
__global__ __launch_bounds__(256) void k_out(
    const u16* __restrict__ abar, const u16* __restrict__ wpT,
    const float* __restrict__ bp, const float* __restrict__ skip,
    float* __restrict__ out)
{
  __shared__ alignas(16) u16 Als[64*136];
  int tid = threadIdx.x;
  int R0 = blockIdx.x * 64;
  #pragma unroll
  for (int i = 0; i < 4; i++){
    int c = tid + i*256;
    int row = c >> 4, part = c & 15;
    *(u16x8*)&Als[row*136 + part*8] = *(const u16x8*)(abar + (size_t)(R0+row)*128 + part*8);
  }
  __syncthreads();
  int wave = tid >> 6, lane = tid & 63, lm = lane & 31, lh = lane >> 5;
  bf16x8 bfr[8];
  const u16* wrow = wpT + (32*wave + lm)*128 + lh*8;
  #pragma unroll
  for (int ks = 0; ks < 8; ks++) bfr[ks] = *(const bf16x8*)(wrow + ks*16);
  f32x16 acc0, acc1;
  #pragma unroll
  for (int r = 0; r < 16; r++){ acc0[r]=0.f; acc1[r]=0.f; }
  #pragma unroll
  for (int ks = 0; ks < 8; ks++){
    bf16x8 a0 = *(const bf16x8*)&Als[lm*136      + ks*16 + lh*8];
    bf16x8 a1 = *(const bf16x8*)&Als[(32+lm)*136 + ks*16 + lh*8];
    acc0 = mfma_bf16(a0, bfr[ks], acc0);
    acc1 = mfma_bf16(a1, bfr[ks], acc1);
  }
  float bias = bp[32*wave + lm];
  #pragma unroll
  for (int r = 0; r < 16; r++){
    int row0 = (r&3) + 8*(r>>2) + 4*lh;
    size_t f0 = (size_t)(R0 + row0)*128 + 32*wave + lm;
    out[f0] = acc0[r] + bias + skip[f0];
    size_t f1 = (size_t)(R0 + 32 + row0)*128 + 32*wave + lm;
    out[f1] = acc1[r] + bias + skip[f1];
  }
}

// ---------------------------------------------------------------- launch
extern "C" void kernel_launch(void* const* d_in, const int* in_sizes, int n_in,
                              void* d_out, int out_size, void* d_ws, size_t ws_size,
                              hipStream_t stream)
{
  const float* q    = (const float*)d_in[0];
  const float* k    = (const float*)d_in[1];
  const float* v    = (const float*)d_in[2];
  const float* skip = (const float*)d_in[3];
  const float* gq   = (const float*)d_in[4];
  const float* betq = (const float*)d_in[5];
  const float* gk   = (const float*)d_in[6];
  const float* betk = (const float*)d_in[7];
  const float* gv   = (const float*)d_in[8];
  const float* betv = (const float*)d_in[9];
  const float* wq   = (const float*)d_in[10];
  const float* bq   = (const float*)d_in[11];
  const float* wk   = (const float*)d_in[12];
  const float* bk   = (const float*)d_in[13];
  const float* wv   = (const float*)d_in[14];
  const float* bv   = (const float*)d_in[15];
  const float* wp   = (const float*)d_in[16];
  const float* bp   = (const float*)d_in[17];
  float* out = (float*)d_out;

  char* ws = (char*)d_ws;
  u16* wqT = (u16*)ws;                 // 16384 u16 each
  u16* wkT = wqT + 16384;
  u16* wvT = wkT + 16384;
  u16* wpT = wvT + 16384;
  float* bq2 = (float*)(ws + 131072);  // 128 f32 each
  float* bk2 = bq2 + 128;
  float* bv2 = bk2 + 128;
  float* uq2 = bv2 + 128;
  float* uk2 = uq2 + 128;
  float* uv2 = uk2 + 128;
  u16* qh = (u16*)(ws + 134144);       // [128][4][384][32] bf16 = 12.58 MB each
  u16* kh = qh + 6291456;
  u16* vh = kh + 6291456;
  u16* abar = vh + 6291456;            // [8192][128] bf16 = 2 MB

  k_prep  <<<16,   128, 0, stream>>>(wq,bq,gq,betq, wk,bk,gk,betk, wv,bv,gv,betv, wp,
                                     wqT,wkT,wvT,wpT, bq2,bk2,bv2, uq2,uk2,uv2);
  k_lnproj<<<2304, 256, 0, stream>>>(q,k,v, wqT,wkT,wvT, bq2,bk2,bv2, uq2,uk2,uv2, qh,kh,vh);
  k_attn  <<<512,  768, 0, stream>>>(qh,kh,vh, abar);
  k_out   <<<128,  256, 0, stream>>>(abar, wpT, bp, skip, out);
}

// Round 3
// 221.435 us; speedup vs baseline: 1.0392x; 1.0124x over previous
//
#include <hip/hip_runtime.h>

// CrossWinAttention on MI355X (gfx950), bf16 MFMA pipeline. R3:
//  - k_attn: raw v_exp_f32 via __builtin_amdgcn_exp2f (scores bounded, no
//    guards needed) + hardware bf16 cvt via (__bf16) casts (v_cvt_pk_bf16_f32)
//    -> softmax epilogue VALU cut ~3x. rcp-then-shfl normalization.
//  - k_prep: parallel rewrite (4 blocks x 512 thr, coalesced load -> LDS
//    transpose -> 4-way parallel bias/u reduction). Old version was 16 blocks
//    of serial strided loads = latency-bound.
//  - k_lnproj: hardware bf16 casts in loader + epilogue.
//  - S^T trick (P in registers), LN folded into GEMM epilogue, mean-over-N
//    folded before final projection, softmax scale*log2e folded into wq/bq.

typedef unsigned short u16;
typedef __bf16 bf16x8 __attribute__((ext_vector_type(8)));
typedef __bf16 bf16x4 __attribute__((ext_vector_type(4)));
typedef float  f32x16 __attribute__((ext_vector_type(16)));
typedef unsigned short u16x8 __attribute__((ext_vector_type(8)));

union U8 { u16x8 u; bf16x8 b; };

#if __has_builtin(__builtin_amdgcn_exp2f)
#define EXP2(x) __builtin_amdgcn_exp2f(x)
#else
#define EXP2(x) exp2f(x)
#endif

__device__ __forceinline__ f32x16 mfma_bf16(bf16x8 a, bf16x8 b, f32x16 c){
  return __builtin_amdgcn_mfma_f32_32x32x16_bf16(a, b, c, 0, 0, 0);
}

// 32x32x16 bf16 fragment conventions:
//  A: m=lane&31, k=(lane>>5)*8+j ; B: n=lane&31, k=(lane>>5)*8+j
//  C/D: col=lane&31, row=(reg&3)+8*(reg>>2)+4*(lane>>5)   [verified m74/m101]
// S^T = mfma(K, Q): col = q (fixed per lane), reg axis = keys; regs 0..7 are
// exactly the PV A-slots for keys 4lh+{0-3,8-11}, regs 8..15 for +16. V^T is
// stored with the matching key swizzle so PV B-fragments are single 16B reads.

// ---------------------------------------------------------------- k_prep
// 4 blocks (one per weight) x 512 thr. Coalesced load -> LDS -> transposed
// bf16 write + parallel bias'/u reduction.
__global__ __launch_bounds__(512) void k_prep(
    const float* __restrict__ wq, const float* __restrict__ bq,
    const float* __restrict__ gq, const float* __restrict__ betq,
    const float* __restrict__ wk, const float* __restrict__ bk,
    const float* __restrict__ gk, const float* __restrict__ betk,
    const float* __restrict__ wv, const float* __restrict__ bv,
    const float* __restrict__ gv, const float* __restrict__ betv,
    const float* __restrict__ wp,
    u16* __restrict__ wqT, u16* __restrict__ wkT, u16* __restrict__ wvT, u16* __restrict__ wpT,
    float* __restrict__ bq2, float* __restrict__ bk2, float* __restrict__ bv2,
    float* __restrict__ uq2, float* __restrict__ uk2, float* __restrict__ uv2)
{
  __shared__ float wls[128*129];
  __shared__ float gls[128], bls[128];
  __shared__ float redb[512], redu[512];
  const float ALPHA_Q = 0.17677669529663687f * 1.4426950408889634f; // DH^-0.5 * log2(e)
  int wsel = blockIdx.x, tid = threadIdx.x;
  const float *w, *bb, *g, *bet; u16* wT; float *b2, *u2; float alpha;
  if (wsel == 0){ w=wq; bb=bq; g=gq; bet=betq; wT=wqT; b2=bq2; u2=uq2; alpha=ALPHA_Q; }
  else if (wsel == 1){ w=wk; bb=bk; g=gk; bet=betk; wT=wkT; b2=bk2; u2=uk2; alpha=1.f; }
  else if (wsel == 2){ w=wv; bb=bv; g=gv; bet=betv; wT=wvT; b2=bv2; u2=uv2; alpha=1.f; }
  else { w=wp; bb=nullptr; g=nullptr; bet=nullptr; wT=wpT; b2=nullptr; u2=nullptr; alpha=1.f; }

  if (tid < 128){
    gls[tid] = g ? g[tid] : 1.f;
    bls[tid] = bet ? bet[tid] : 0.f;
  }
  const float4* w4 = (const float4*)w;
  #pragma unroll
  for (int i = 0; i < 8; i++){
    int idx = tid + i*512;              // 4096 float4s
    int row = idx >> 5, c4 = (idx & 31) * 4;   // row = k, c4 = n base
    float4 x = w4[idx];
    wls[row*129 + c4 + 0] = x.x;
    wls[row*129 + c4 + 1] = x.y;
    wls[row*129 + c4 + 2] = x.z;
    wls[row*129 + c4 + 3] = x.w;
  }
  __syncthreads();
  int n = tid >> 2, qp = tid & 3;
  float sb = 0.f, su = 0.f;
  alignas(16) __bf16 tmp[32];
  #pragma unroll
  for (int kk = 0; kk < 32; kk++){
    int k2 = qp*32 + kk;
    float wv_ = wls[k2*129 + n];
    float gv_ = gls[k2];
    sb += bls[k2] * wv_;
    su += gv_ * wv_;
    tmp[kk] = (__bf16)(wv_ * gv_ * alpha);
  }
  #pragma unroll
  for (int j = 0; j < 4; j++)
    *(bf16x8*)(wT + n*128 + qp*32 + j*8) = *(bf16x8*)&tmp[j*8];
  redb[tid] = sb; redu[tid] = su;
  __syncthreads();
  if (qp == 0 && bb){
    float s = bb[n] + redb[tid] + redb[tid+1] + redb[tid+2] + redb[tid+3];
    float u = redu[tid] + redu[tid+1] + redu[tid+2] + redu[tid+3];
    b2[n] = s * alpha;
    u2[n] = u * alpha;
  }
}

// ---------------------------------------------------------------- k_lnproj
// grid 2304 = 128 (b,l) * 6 (n) * 3 (q/k/v); 256 thr (4 waves).
// Raw-x bf16 GEMM; LN applied in epilogue: y = r*z - r*m*u2[n] + b2[n].
__global__ __launch_bounds__(256) void k_lnproj(
    const float* __restrict__ qg, const float* __restrict__ kg, const float* __restrict__ vg,
    const u16* __restrict__ wqT, const u16* __restrict__ wkT, const u16* __restrict__ wvT,
    const float* __restrict__ bq2, const float* __restrict__ bk2, const float* __restrict__ bv2,
    const float* __restrict__ uq2, const float* __restrict__ uk2, const float* __restrict__ uv2,
    u16* __restrict__ qh, u16* __restrict__ kh, u16* __restrict__ vh)
{
  __shared__ alignas(16) u16 Abf[64*136];
  __shared__ float s1s[64], s2s[64];     // reused as rs / rm after barrier1
  int bid = blockIdx.x, tid = threadIdx.x;
  int which = bid % 3;
  int t = bid / 3;
  int n = t % 6, bl = t / 6;
  const float* src; const u16* wT; const float *b2, *u2; u16* dstb;
  if (which == 0){ src=qg; wT=wqT; b2=bq2; u2=uq2; dstb=qh; }
  else if (which == 1){ src=kg; wT=wkT; b2=bk2; u2=uk2; dstb=kh; }
  else { src=vg; wT=wvT; b2=bv2; u2=uv2; dstb=vh; }
  int b = bl >> 6, l = bl & 63;
  const float4* s4 = (const float4*)(src + (size_t)((b*6 + n)*64 + l)*64*128);
  #pragma unroll
  for (int i = 0; i < 8; i++){
    int idx = tid + i*256;
    int row = idx >> 5, c4 = idx & 31;
    float4 xv = s4[idx];
    float s1 = xv.x + xv.y + xv.z + xv.w;
    float s2 = xv.x*xv.x + xv.y*xv.y + xv.z*xv.z + xv.w*xv.w;
    #pragma unroll
    for (int m = 1; m < 32; m <<= 1){
      s1 += __shfl_xor(s1, m, 64);
      s2 += __shfl_xor(s2, m, 64);
    }
    if (c4 == 0){ s1s[row] = s1; s2s[row] = s2; }
    bf16x4 pk;
    pk[0] = (__bf16)xv.x; pk[1] = (__bf16)xv.y;
    pk[2] = (__bf16)xv.z; pk[3] = (__bf16)xv.w;
    *(bf16x4*)&Abf[row*136 + c4*4] = pk;
  }
  __syncthreads();
  if (tid < 64){
    float m = s1s[tid] * (1.f/128.f);
    float r = rsqrtf(s2s[tid] * (1.f/128.f) - m*m + 1e-5f);
    s1s[tid] = r;          // rs
    s2s[tid] = r * m;      // rm
  }
  int wave = tid >> 6, lane = tid & 63, lm = lane & 31, lh = lane >> 5;
  bf16x8 bfr[8];
  const u16* wrow = wT + (32*wave + lm)*128 + lh*8;
  #pragma unroll
  for (int ks = 0; ks < 8; ks++) bfr[ks] = *(const bf16x8*)(wrow + ks*16);
  f32x16 acc0, acc1;
  #pragma unroll
  for (int r = 0; r < 16; r++){ acc0[r]=0.f; acc1[r]=0.f; }
  #pragma unroll
  for (int ks = 0; ks < 8; ks++){
    bf16x8 a0 = *(const bf16x8*)&Abf[lm*136       + ks*16 + lh*8];
    bf16x8 a1 = *(const bf16x8*)&Abf[(32+lm)*136  + ks*16 + lh*8];
    acc0 = mfma_bf16(a0, bfr[ks], acc0);
    acc1 = mfma_bf16(a1, bfr[ks], acc1);
  }
  __syncthreads();   // rs/rm ready (cheap: all waves exit MFMA together)
  int col = 32*wave + lm;
  float u2c = u2[col], bc = b2[col];
  u16* dst = dstb + ((size_t)(bl*4 + wave)*384 + n*64)*32 + lm;
  #pragma unroll
  for (int r = 0; r < 16; r++){
    int row0 = (r&3) + 8*(r>>2) + 4*lh;
    float y0 = s1s[row0]     * acc0[r] - s2s[row0]     * u2c + bc;
    float y1 = s1s[row0+32]  * acc1[r] - s2s[row0+32]  * u2c + bc;
    *(__bf16*)&dst[(size_t)row0*32]      = (__bf16)y0;
    *(__bf16*)&dst[(size_t)(32+row0)*32] = (__bf16)y1;
  }
}

// ---------------------------------------------------------------- k_attn
// grid 512 = (b,l)*h; 768 thr = 12 waves; wave w: n = w>>1, q-half = w&1.
// S^T trick keeps P in registers; V^T in LDS, key-swizzled. LDS 34.3 KB.
__global__ __launch_bounds__(768, 6) void k_attn(
    const u16* __restrict__ qh, const u16* __restrict__ kh, const u16* __restrict__ vh,
    u16* __restrict__ abar)
{
  __shared__ alignas(16) u16 vts[32*408];   // V^T [dh][swizzled key], stride 408
  __shared__ float abar_s[64*32];
  int bid = blockIdx.x, tid = threadIdx.x;
  int h = bid & 3, bl = bid >> 2;
  const u16* qb = qh + (size_t)bid * (384*32);
  const u16* kb = kh + (size_t)bid * (384*32);
  const u16* vb = vh + (size_t)bid * (384*32);

  // stage V transposed + key-swizzled: key u (mod 32) at a-group perm{0,2,1,3,4,6,5,7}
  #pragma unroll
  for (int i = 0; i < 2; i++){
    int c = tid + i*768;               // 1536 16B chunks
    int key = c >> 2, part = c & 3;
    int u = key & 31, tt = key >> 5;
    int a = u >> 2;
    int anew = (a & 4) | ((a & 1) << 1) | ((a >> 1) & 1);
    int pos = tt*32 + anew*4 + (u & 3);
    u16x8 vv = *(const u16x8*)(vb + key*32 + part*8);
    #pragma unroll
    for (int j = 0; j < 8; j++) vts[(part*8 + j)*408 + pos] = vv[j];
  }
  for (int idx = tid; idx < 2048; idx += 768) abar_s[idx] = 0.f;
  __syncthreads();

  int wave = tid >> 6, lane = tid & 63, lm = lane & 31, lh = lane >> 5;
  int n = wave >> 1, qoff = (wave & 1) * 32;
  int qrow = n*64 + qoff + lm;

  bf16x8 qf0 = *(const bf16x8*)(qb + qrow*32 +      lh*8);
  bf16x8 qf1 = *(const bf16x8*)(qb + qrow*32 + 16 + lh*8);

  f32x16 oacc;
  #pragma unroll
  for (int r = 0; r < 16; r++) oacc[r] = 0.f;
  float sle = 0.f;

  const u16* vrow = &vts[lm*408 + 8*lh];

  for (int kt = 0; kt < 12; kt++){
    int K0 = kt*32;
    bf16x8 kf0 = *(const bf16x8*)(kb + (K0+lm)*32 +      lh*8);
    bf16x8 kf1 = *(const bf16x8*)(kb + (K0+lm)*32 + 16 + lh*8);
    f32x16 s;
    #pragma unroll
    for (int r = 0; r < 16; r++) s[r] = 0.f;
    s = mfma_bf16(kf0, qf0, s);        // S^T: col = q = lm, regs = keys
    s = mfma_bf16(kf1, qf1, s);
    U8 p0, p1;
    #pragma unroll
    for (int r = 0; r < 8; r++){
      float e0 = EXP2(s[r]);
      float e1 = EXP2(s[r+8]);
      sle += e0 + e1;
      p0.b[r] = (__bf16)e0;            // v_cvt_pk_bf16_f32 (RNE) on gfx950
      p1.b[r] = (__bf16)e1;
    }
    U8 vb0, vb1;
    vb0.u = *(const u16x8*)(vrow + K0);       // keys 4lh+{0-3,8-11} (swizzled)
    vb1.u = *(const u16x8*)(vrow + K0 + 16);  // keys 16+4lh+{0-3,8-11}
    oacc = mfma_bf16(p0.b, vb0.b, oacc);
    oacc = mfma_bf16(p1.b, vb1.b, oacc);
  }

  // total row sum for q = lm: combine lh halves, then broadcast reciprocals
  sle += __shfl_xor(sle, 32, 64);
  float inv = (1.f/6.f) / sle;

  // oacc lane(lm,lh) reg r = O[q = qoff+(r&3)+8*(r>>2)+4*lh][dh = lm]
  #pragma unroll
  for (int r = 0; r < 16; r++){
    int q_l = (r&3) + 8*(r>>2) + 4*lh;
    float o = oacc[r] * __shfl(inv, q_l, 64);
    atomicAdd(&abar_s[(qoff + q_l)*32 + lm], o);
  }
  __syncthreads();
  u16* ob = abar + (size_t)(bl*64)*128 + h*32;
  for (int idx = tid; idx < 2048; idx += 768){
    int w12 = idx >> 5, dh = idx & 31;
    *(__bf16*)&ob[(size_t)w12*128 + dh] = (__bf16)abar_s[idx];
  }
}

// ---------------------------------------------------------------- k_out
__global__ __launch_bounds__(256) void k_out(
    const u16* __restrict__ abar, const u16* __restrict__ wpT,
    const float* __restrict__ bp, const float* __restrict__ skip,
    float* __restrict__ out)
{
  __shared__ alignas(16) u16 Als[64*136];
  int tid = threadIdx.x;
  int R0 = blockIdx.x * 64;
  #pragma unroll
  for (int i = 0; i < 4; i++){
    int c = tid + i*256;
    int row = c >> 4, part = c & 15;
    *(u16x8*)&Als[row*136 + part*8] = *(const u16x8*)(abar + (size_t)(R0+row)*128 + part*8);
  }
  __syncthreads();
  int wave = tid >> 6, lane = tid & 63, lm = lane & 31, lh = lane >> 5;
  bf16x8 bfr[8];
  const u16* wrow = wpT + (32*wave + lm)*128 + lh*8;
  #pragma unroll
  for (int ks = 0; ks < 8; ks++) bfr[ks] = *(const bf16x8*)(wrow + ks*16);
  f32x16 acc0, acc1;
  #pragma unroll
  for (int r = 0; r < 16; r++){ acc0[r]=0.f; acc1[r]=0.f; }
  #pragma unroll
  for (int ks = 0; ks < 8; ks++){
    bf16x8 a0 = *(const bf16x8*)&Als[lm*136      + ks*16 + lh*8];
    bf16x8 a1 = *(const bf16x8*)&Als[(32+lm)*136 + ks*16 + lh*8];
    acc0 = mfma_bf16(a0, bfr[ks], acc0);
    acc1 = mfma_bf16(a1, bfr[ks], acc1);
  }
  float bias = bp[32*wave + lm];
  #pragma unroll
  for (int r = 0; r < 16; r++){
    int row0 = (r&3) + 8*(r>>2) + 4*lh;
    size_t f0 = (size_t)(R0 + row0)*128 + 32*wave + lm;
    out[f0] = acc0[r] + bias + skip[f0];
    size_t f1 = (size_t)(R0 + 32 + row0)*128 + 32*wave + lm;
    out[f1] = acc1[r] + bias + skip[f1];
  }
}

// ---------------------------------------------------------------- launch
extern "C" void kernel_launch(void* const* d_in, const int* in_sizes, int n_in,
                              void* d_out, int out_size, void* d_ws, size_t ws_size,
                              hipStream_t stream)
{
  const float* q    = (const float*)d_in[0];
  const float* k    = (const float*)d_in[1];
  const float* v    = (const float*)d_in[2];
  const float* skip = (const float*)d_in[3];
  const float* gq   = (const float*)d_in[4];
  const float* betq = (const float*)d_in[5];
  const float* gk   = (const float*)d_in[6];
  const float* betk = (const float*)d_in[7];
  const float* gv   = (const float*)d_in[8];
  const float* betv = (const float*)d_in[9];
  const float* wq   = (const float*)d_in[10];
  const float* bq   = (const float*)d_in[11];
  const float* wk   = (const float*)d_in[12];
  const float* bk   = (const float*)d_in[13];
  const float* wv   = (const float*)d_in[14];
  const float* bv   = (const float*)d_in[15];
  const float* wp   = (const float*)d_in[16];
  const float* bp   = (const float*)d_in[17];
  float* out = (float*)d_out;

  char* ws = (char*)d_ws;
  u16* wqT = (u16*)ws;                 // 16384 u16 each
  u16* wkT = wqT + 16384;
  u16* wvT = wkT + 16384;
  u16* wpT = wvT + 16384;
  float* bq2 = (float*)(ws + 131072);  // 128 f32 each
  float* bk2 = bq2 + 128;
  float* bv2 = bk2 + 128;
  float* uq2 = bv2 + 128;
  float* uk2 = uq2 + 128;
  float* uv2 = uk2 + 128;
  u16* qh = (u16*)(ws + 134144);       // [128][4][384][32] bf16 = 12.58 MB each
  u16* kh = qh + 6291456;
  u16* vh = kh + 6291456;
  u16* abar = vh + 6291456;            // [8192][128] bf16 = 2 MB

  k_prep  <<<4,    512, 0, stream>>>(wq,bq,gq,betq, wk,bk,gk,betk, wv,bv,gv,betv, wp,
                                     wqT,wkT,wvT,wpT, bq2,bk2,bv2, uq2,uk2,uv2);
  k_lnproj<<<2304, 256, 0, stream>>>(q,k,v, wqT,wkT,wvT, bq2,bk2,bv2, uq2,uk2,uv2, qh,kh,vh);
  k_attn  <<<512,  768, 0, stream>>>(qh,kh,vh, abar);
  k_out   <<<128,  256, 0, stream>>>(abar, wpT, bp, skip, out);
}

// Round 4
// 221.320 us; speedup vs baseline: 1.0398x; 1.0005x over previous
//
#include <hip/hip_runtime.h>

// CrossWinAttention on MI355X (gfx950), bf16 MFMA pipeline. R4:
//  - k_attn: register double-buffered software pipeline — prefetch kt+1's
//    K (global) and V (LDS) fragments while computing kt; full unroll.
//    Removes load latency from the serial S->exp->PV chain (R3 was 75% stall
//    with all pipes idle: latency-bound).
//  - k_lnproj: quad-per-row loads; per-thread partial sums + 2 shfl_xor
//    replace 8x10 shuffle chains; LN stats finalized in load phase -> one
//    barrier total.
//  - Carried: S^T trick (P in registers), LN folded into GEMM epilogue,
//    mean-over-N folded before final projection, scale*log2e folded into
//    wq/bq (exp2-only softmax, no max subtraction), v_exp_f32 + hw bf16 cvt.

typedef unsigned short u16;
typedef __bf16 bf16x8 __attribute__((ext_vector_type(8)));
typedef __bf16 bf16x4 __attribute__((ext_vector_type(4)));
typedef float  f32x16 __attribute__((ext_vector_type(16)));
typedef unsigned short u16x8 __attribute__((ext_vector_type(8)));

union U8 { u16x8 u; bf16x8 b; };

#if __has_builtin(__builtin_amdgcn_exp2f)
#define EXP2(x) __builtin_amdgcn_exp2f(x)
#else
#define EXP2(x) exp2f(x)
#endif

__device__ __forceinline__ f32x16 mfma_bf16(bf16x8 a, bf16x8 b, f32x16 c){
  return __builtin_amdgcn_mfma_f32_32x32x16_bf16(a, b, c, 0, 0, 0);
}

// 32x32x16 bf16 fragment conventions:
//  A: m=lane&31, k=(lane>>5)*8+j ; B: n=lane&31, k=(lane>>5)*8+j
//  C/D: col=lane&31, row=(reg&3)+8*(reg>>2)+4*(lane>>5)   [verified m74/m101]
// S^T = mfma(K, Q): col = q (fixed per lane), reg axis = keys; regs 0..7 are
// exactly the PV A-slots for keys 4lh+{0-3,8-11}, regs 8..15 for +16. V^T is
// stored with the matching key swizzle so PV B-fragments are single 16B reads.

// ---------------------------------------------------------------- k_prep
// 4 blocks (one per weight) x 512 thr. Coalesced load -> LDS -> transposed
// bf16 write + parallel bias'/u reduction.
__global__ __launch_bounds__(512) void k_prep(
    const float* __restrict__ wq, const float* __restrict__ bq,
    const float* __restrict__ gq, const float* __restrict__ betq,
    const float* __restrict__ wk, const float* __restrict__ bk,
    const float* __restrict__ gk, const float* __restrict__ betk,
    const float* __restrict__ wv, const float* __restrict__ bv,
    const float* __restrict__ gv, const float* __restrict__ betv,
    const float* __restrict__ wp,
    u16* __restrict__ wqT, u16* __restrict__ wkT, u16* __restrict__ wvT, u16* __restrict__ wpT,
    float* __restrict__ bq2, float* __restrict__ bk2, float* __restrict__ bv2,
    float* __restrict__ uq2, float* __restrict__ uk2, float* __restrict__ uv2)
{
  __shared__ float wls[128*129];
  __shared__ float gls[128], bls[128];
  __shared__ float redb[512], redu[512];
  const float ALPHA_Q = 0.17677669529663687f * 1.4426950408889634f; // DH^-0.5 * log2(e)
  int wsel = blockIdx.x, tid = threadIdx.x;
  const float *w, *bb, *g, *bet; u16* wT; float *b2, *u2; float alpha;
  if (wsel == 0){ w=wq; bb=bq; g=gq; bet=betq; wT=wqT; b2=bq2; u2=uq2; alpha=ALPHA_Q; }
  else if (wsel == 1){ w=wk; bb=bk; g=gk; bet=betk; wT=wkT; b2=bk2; u2=uk2; alpha=1.f; }
  else if (wsel == 2){ w=wv; bb=bv; g=gv; bet=betv; wT=wvT; b2=bv2; u2=uv2; alpha=1.f; }
  else { w=wp; bb=nullptr; g=nullptr; bet=nullptr; wT=wpT; b2=nullptr; u2=nullptr; alpha=1.f; }

  if (tid < 128){
    gls[tid] = g ? g[tid] : 1.f;
    bls[tid] = bet ? bet[tid] : 0.f;
  }
  const float4* w4 = (const float4*)w;
  #pragma unroll
  for (int i = 0; i < 8; i++){
    int idx = tid + i*512;              // 4096 float4s
    int row = idx >> 5, c4 = (idx & 31) * 4;   // row = k, c4 = n base
    float4 x = w4[idx];
    wls[row*129 + c4 + 0] = x.x;
    wls[row*129 + c4 + 1] = x.y;
    wls[row*129 + c4 + 2] = x.z;
    wls[row*129 + c4 + 3] = x.w;
  }
  __syncthreads();
  int n = tid >> 2, qp = tid & 3;
  float sb = 0.f, su = 0.f;
  alignas(16) __bf16 tmp[32];
  #pragma unroll
  for (int kk = 0; kk < 32; kk++){
    int k2 = qp*32 + kk;
    float wv_ = wls[k2*129 + n];
    float gv_ = gls[k2];
    sb += bls[k2] * wv_;
    su += gv_ * wv_;
    tmp[kk] = (__bf16)(wv_ * gv_ * alpha);
  }
  #pragma unroll
  for (int j = 0; j < 4; j++)
    *(bf16x8*)(wT + n*128 + qp*32 + j*8) = *(bf16x8*)&tmp[j*8];
  redb[tid] = sb; redu[tid] = su;
  __syncthreads();
  if (qp == 0 && bb){
    float s = bb[n] + redb[tid] + redb[tid+1] + redb[tid+2] + redb[tid+3];
    float u = redu[tid] + redu[tid+1] + redu[tid+2] + redu[tid+3];
    b2[n] = s * alpha;
    u2[n] = u * alpha;
  }
}

// ---------------------------------------------------------------- k_lnproj
// grid 2304 = 128 (b,l) * 6 (n) * 3 (q/k/v); 256 thr (4 waves).
// Raw-x bf16 GEMM; LN applied in epilogue: y = r*z - r*m*u2[n] + b2[n].
// Thread (row=tid>>2, j=tid&3) owns 32 elems of one row: private partial
// sums + 2 shfl_xor in the quad; stats final before the single barrier.
__global__ __launch_bounds__(256) void k_lnproj(
    const float* __restrict__ qg, const float* __restrict__ kg, const float* __restrict__ vg,
    const u16* __restrict__ wqT, const u16* __restrict__ wkT, const u16* __restrict__ wvT,
    const float* __restrict__ bq2, const float* __restrict__ bk2, const float* __restrict__ bv2,
    const float* __restrict__ uq2, const float* __restrict__ uk2, const float* __restrict__ uv2,
    u16* __restrict__ qh, u16* __restrict__ kh, u16* __restrict__ vh)
{
  __shared__ alignas(16) u16 Abf[64*136];
  __shared__ float s1s[64], s2s[64];     // rs / rm
  int bid = blockIdx.x, tid = threadIdx.x;
  int which = bid % 3;
  int t = bid / 3;
  int n = t % 6, bl = t / 6;
  const float* src; const u16* wT; const float *b2, *u2; u16* dstb;
  if (which == 0){ src=qg; wT=wqT; b2=bq2; u2=uq2; dstb=qh; }
  else if (which == 1){ src=kg; wT=wkT; b2=bk2; u2=uk2; dstb=kh; }
  else { src=vg; wT=wvT; b2=bv2; u2=uv2; dstb=vh; }
  int b = bl >> 6, l = bl & 63;
  const float4* s4 = (const float4*)(src + (size_t)((b*6 + n)*64 + l)*64*128);
  int row = tid >> 2, j = tid & 3;
  float s1 = 0.f, s2 = 0.f;
  #pragma unroll
  for (int i = 0; i < 8; i++){
    float4 xv = s4[row*32 + i*4 + j];
    s1 += xv.x + xv.y + xv.z + xv.w;
    s2 += xv.x*xv.x + xv.y*xv.y + xv.z*xv.z + xv.w*xv.w;
    bf16x4 pk;
    pk[0] = (__bf16)xv.x; pk[1] = (__bf16)xv.y;
    pk[2] = (__bf16)xv.z; pk[3] = (__bf16)xv.w;
    *(bf16x4*)&Abf[row*136 + (i*4 + j)*4] = pk;
  }
  s1 += __shfl_xor(s1, 1, 64); s1 += __shfl_xor(s1, 2, 64);
  s2 += __shfl_xor(s2, 1, 64); s2 += __shfl_xor(s2, 2, 64);
  if (j == 0){
    float m = s1 * (1.f/128.f);
    float r = rsqrtf(s2 * (1.f/128.f) - m*m + 1e-5f);
    s1s[row] = r;          // rs
    s2s[row] = r * m;      // rm
  }
  __syncthreads();
  int wave = tid >> 6, lane = tid & 63, lm = lane & 31, lh = lane >> 5;
  bf16x8 bfr[8];
  const u16* wrow = wT + (32*wave + lm)*128 + lh*8;
  #pragma unroll
  for (int ks = 0; ks < 8; ks++) bfr[ks] = *(const bf16x8*)(wrow + ks*16);
  f32x16 acc0, acc1;
  #pragma unroll
  for (int r = 0; r < 16; r++){ acc0[r]=0.f; acc1[r]=0.f; }
  #pragma unroll
  for (int ks = 0; ks < 8; ks++){
    bf16x8 a0 = *(const bf16x8*)&Abf[lm*136       + ks*16 + lh*8];
    bf16x8 a1 = *(const bf16x8*)&Abf[(32+lm)*136  + ks*16 + lh*8];
    acc0 = mfma_bf16(a0, bfr[ks], acc0);
    acc1 = mfma_bf16(a1, bfr[ks], acc1);
  }
  int col = 32*wave + lm;
  float u2c = u2[col], bc = b2[col];
  u16* dst = dstb + ((size_t)(bl*4 + wave)*384 + n*64)*32 + lm;
  #pragma unroll
  for (int r = 0; r < 16; r++){
    int row0 = (r&3) + 8*(r>>2) + 4*lh;
    float y0 = s1s[row0]     * acc0[r] - s2s[row0]     * u2c + bc;
    float y1 = s1s[row0+32]  * acc1[r] - s2s[row0+32]  * u2c + bc;
    *(__bf16*)&dst[(size_t)row0*32]      = (__bf16)y0;
    *(__bf16*)&dst[(size_t)(32+row0)*32] = (__bf16)y1;
  }
}

// ---------------------------------------------------------------- k_attn
// grid 512 = (b,l)*h; 768 thr = 12 waves; wave w: n = w>>1, q-half = w&1.
// Register double-buffered K/V pipeline; S^T trick keeps P in registers.
__global__ __launch_bounds__(768, 6) void k_attn(
    const u16* __restrict__ qh, const u16* __restrict__ kh, const u16* __restrict__ vh,
    u16* __restrict__ abar)
{
  __shared__ alignas(16) u16 vts[32*408];   // V^T [dh][swizzled key], stride 408
  __shared__ float abar_s[64*32];
  int bid = blockIdx.x, tid = threadIdx.x;
  int h = bid & 3, bl = bid >> 2;
  const u16* qb = qh + (size_t)bid * (384*32);
  const u16* kb = kh + (size_t)bid * (384*32);
  const u16* vb = vh + (size_t)bid * (384*32);

  int wave = tid >> 6, lane = tid & 63, lm = lane & 31, lh = lane >> 5;
  int n = wave >> 1, qoff = (wave & 1) * 32;
  int qrow = n*64 + qoff + lm;

  // issue Q + kt=0 K loads before staging (independent of LDS)
  bf16x8 qf0 = *(const bf16x8*)(qb + qrow*32 +      lh*8);
  bf16x8 qf1 = *(const bf16x8*)(qb + qrow*32 + 16 + lh*8);
  bf16x8 kf0[2], kf1[2];
  kf0[0] = *(const bf16x8*)(kb + lm*32 +      lh*8);
  kf1[0] = *(const bf16x8*)(kb + lm*32 + 16 + lh*8);

  // stage V transposed + key-swizzled: key u (mod 32) at a-group perm{0,2,1,3,4,6,5,7}
  #pragma unroll
  for (int i = 0; i < 2; i++){
    int c = tid + i*768;               // 1536 16B chunks
    int key = c >> 2, part = c & 3;
    int u = key & 31, tt = key >> 5;
    int a = u >> 2;
    int anew = (a & 4) | ((a & 1) << 1) | ((a >> 1) & 1);
    int pos = tt*32 + anew*4 + (u & 3);
    u16x8 vv = *(const u16x8*)(vb + key*32 + part*8);
    #pragma unroll
    for (int jj = 0; jj < 8; jj++) vts[(part*8 + jj)*408 + pos] = vv[jj];
  }
  for (int idx = tid; idx < 2048; idx += 768) abar_s[idx] = 0.f;
  __syncthreads();

  const u16* vrow = &vts[lm*408 + 8*lh];
  U8 v0[2], v1[2];
  v0[0].u = *(const u16x8*)(vrow);
  v1[0].u = *(const u16x8*)(vrow + 16);

  f32x16 oacc;
  #pragma unroll
  for (int r = 0; r < 16; r++) oacc[r] = 0.f;
  float sle = 0.f;

  #pragma unroll
  for (int kt = 0; kt < 12; kt++){
    int cur = kt & 1, nxt = cur ^ 1;
    if (kt < 11){
      int K1 = (kt+1)*32;
      kf0[nxt] = *(const bf16x8*)(kb + (K1+lm)*32 +      lh*8);
      kf1[nxt] = *(const bf16x8*)(kb + (K1+lm)*32 + 16 + lh*8);
      v0[nxt].u = *(const u16x8*)(vrow + K1);
      v1[nxt].u = *(const u16x8*)(vrow + K1 + 16);
    }
    f32x16 s;
    #pragma unroll
    for (int r = 0; r < 16; r++) s[r] = 0.f;
    s = mfma_bf16(kf0[cur], qf0, s);   // S^T: col = q = lm, regs = keys
    s = mfma_bf16(kf1[cur], qf1, s);
    U8 p0, p1;
    #pragma unroll
    for (int r = 0; r < 8; r++){
      float e0 = EXP2(s[r]);
      float e1 = EXP2(s[r+8]);
      sle += e0 + e1;
      p0.b[r] = (__bf16)e0;            // v_cvt_pk_bf16_f32 (RNE)
      p1.b[r] = (__bf16)e1;
    }
    oacc = mfma_bf16(p0.b, v0[cur].b, oacc);
    oacc = mfma_bf16(p1.b, v1[cur].b, oacc);
  }

  // total row sum for q = lm: combine lh halves, then broadcast reciprocals
  sle += __shfl_xor(sle, 32, 64);
  float inv = (1.f/6.f) / sle;

  // oacc lane(lm,lh) reg r = O[q = qoff+(r&3)+8*(r>>2)+4*lh][dh = lm]
  #pragma unroll
  for (int r = 0; r < 16; r++){
    int q_l = (r&3) + 8*(r>>2) + 4*lh;
    float o = oacc[r] * __shfl(inv, q_l, 64);
    atomicAdd(&abar_s[(qoff + q_l)*32 + lm], o);
  }
  __syncthreads();
  u16* ob = abar + (size_t)(bl*64)*128 + h*32;
  for (int idx = tid; idx < 2048; idx += 768){
    int w12 = idx >> 5, dh = idx & 31;
    *(__bf16*)&ob[(size_t)w12*128 + dh] = (__bf16)abar_s[idx];
  }
}

// ---------------------------------------------------------------- k_out
__global__ __launch_bounds__(256) void k_out(
    const u16* __restrict__ abar, const u16* __restrict__ wpT,
    const float* __restrict__ bp, const float* __restrict__ skip,
    float* __restrict__ out)
{
  __shared__ alignas(16) u16 Als[64*136];
  int tid = threadIdx.x;
  int R0 = blockIdx.x * 64;
  #pragma unroll
  for (int i = 0; i < 4; i++){
    int c = tid + i*256;
    int row = c >> 4, part = c & 15;
    *(u16x8*)&Als[row*136 + part*8] = *(const u16x8*)(abar + (size_t)(R0+row)*128 + part*8);
  }
  __syncthreads();
  int wave = tid >> 6, lane = tid & 63, lm = lane & 31, lh = lane >> 5;
  bf16x8 bfr[8];
  const u16* wrow = wpT + (32*wave + lm)*128 + lh*8;
  #pragma unroll
  for (int ks = 0; ks < 8; ks++) bfr[ks] = *(const bf16x8*)(wrow + ks*16);
  f32x16 acc0, acc1;
  #pragma unroll
  for (int r = 0; r < 16; r++){ acc0[r]=0.f; acc1[r]=0.f; }
  #pragma unroll
  for (int ks = 0; ks < 8; ks++){
    bf16x8 a0 = *(const bf16x8*)&Als[lm*136      + ks*16 + lh*8];
    bf16x8 a1 = *(const bf16x8*)&Als[(32+lm)*136 + ks*16 + lh*8];
    acc0 = mfma_bf16(a0, bfr[ks], acc0);
    acc1 = mfma_bf16(a1, bfr[ks], acc1);
  }
  float bias = bp[32*wave + lm];
  #pragma unroll
  for (int r = 0; r < 16; r++){
    int row0 = (r&3) + 8*(r>>2) + 4*lh;
    size_t f0 = (size_t)(R0 + row0)*128 + 32*wave + lm;
    out[f0] = acc0[r] + bias + skip[f0];
    size_t f1 = (size_t)(R0 + 32 + row0)*128 + 32*wave + lm;
    out[f1] = acc1[r] + bias + skip[f1];
  }
}

// ---------------------------------------------------------------- launch
extern "C" void kernel_launch(void* const* d_in, const int* in_sizes, int n_in,
                              void* d_out, int out_size, void* d_ws, size_t ws_size,
                              hipStream_t stream)
{
  const float* q    = (const float*)d_in[0];
  const float* k    = (const float*)d_in[1];
  const float* v    = (const float*)d_in[2];
  const float* skip = (const float*)d_in[3];
  const float* gq   = (const float*)d_in[4];
  const float* betq = (const float*)d_in[5];
  const float* gk   = (const float*)d_in[6];
  const float* betk = (const float*)d_in[7];
  const float* gv   = (const float*)d_in[8];
  const float* betv = (const float*)d_in[9];
  const float* wq   = (const float*)d_in[10];
  const float* bq   = (const float*)d_in[11];
  const float* wk   = (const float*)d_in[12];
  const float* bk   = (const float*)d_in[13];
  const float* wv   = (const float*)d_in[14];
  const float* bv   = (const float*)d_in[15];
  const float* wp   = (const float*)d_in[16];
  const float* bp   = (const float*)d_in[17];
  float* out = (float*)d_out;

  char* ws = (char*)d_ws;
  u16* wqT = (u16*)ws;                 // 16384 u16 each
  u16* wkT = wqT + 16384;
  u16* wvT = wkT + 16384;
  u16* wpT = wvT + 16384;
  float* bq2 = (float*)(ws + 131072);  // 128 f32 each
  float* bk2 = bq2 + 128;
  float* bv2 = bk2 + 128;
  float* uq2 = bv2 + 128;
  float* uk2 = uq2 + 128;
  float* uv2 = uk2 + 128;
  u16* qh = (u16*)(ws + 134144);       // [128][4][384][32] bf16 = 12.58 MB each
  u16* kh = qh + 6291456;
  u16* vh = kh + 6291456;
  u16* abar = vh + 6291456;            // [8192][128] bf16 = 2 MB

  k_prep  <<<4,    512, 0, stream>>>(wq,bq,gq,betq, wk,bk,gk,betk, wv,bv,gv,betv, wp,
                                     wqT,wkT,wvT,wpT, bq2,bk2,bv2, uq2,uk2,uv2);
  k_lnproj<<<2304, 256, 0, stream>>>(q,k,v, wqT,wkT,wvT, bq2,bk2,bv2, uq2,uk2,uv2, qh,kh,vh);
  k_attn  <<<512,  768, 0, stream>>>(qh,kh,vh, abar);
  k_out   <<<128,  256, 0, stream>>>(abar, wpT, bp, skip, out);
}

// Round 5
// 213.171 us; speedup vs baseline: 1.0795x; 1.0382x over previous
//
#include <hip/hip_runtime.h>

// CrossWinAttention on MI355X (gfx950), bf16 MFMA pipeline. R5:
//  - k_attn: K staged into LDS in the block prologue (bulk: all misses in
//    flight at once) instead of per-iteration global loads (R3: ~24 serial
//    HBM misses per lead wave = dominant stall; R4 reg-prefetch spilled to
//    scratch: WRITE_SIZE 2->31.6 MB). Inner loop is now LDS-only. K rows
//    padded to 72 B -> ds_read_b64 pairs conflict-free (stride 18 banks,
//    gcd(18,32)=2 -> 16 lanes x 2 banks = all 32 banks).
//    S accumulator split sa/sb -> the two QK MFMAs are independent.
//    No manual prefetch arrays (VGPR cap 85 at 6 waves/EU; ~70 used).
//  - k_lnproj: R4 version kept (quad-per-row loads, ~9 us win).
//  - Carried: S^T trick (P stays in registers), LN folded into GEMM epilogue,
//    mean-over-N folded before final projection, scale*log2e folded into
//    wq/bq (exp2-only softmax, no max subtraction), v_exp_f32 + hw bf16 cvt.

typedef unsigned short u16;
typedef __bf16 bf16x8 __attribute__((ext_vector_type(8)));
typedef __bf16 bf16x4 __attribute__((ext_vector_type(4)));
typedef float  f32x16 __attribute__((ext_vector_type(16)));
typedef unsigned short u16x8 __attribute__((ext_vector_type(8)));
typedef unsigned short u16x4 __attribute__((ext_vector_type(4)));

union U8 { u16x8 u; bf16x8 b; u16x4 h[2]; };

#if __has_builtin(__builtin_amdgcn_exp2f)
#define EXP2(x) __builtin_amdgcn_exp2f(x)
#else
#define EXP2(x) exp2f(x)
#endif

__device__ __forceinline__ f32x16 mfma_bf16(bf16x8 a, bf16x8 b, f32x16 c){
  return __builtin_amdgcn_mfma_f32_32x32x16_bf16(a, b, c, 0, 0, 0);
}

// 32x32x16 bf16 fragment conventions:
//  A: m=lane&31, k=(lane>>5)*8+j ; B: n=lane&31, k=(lane>>5)*8+j
//  C/D: col=lane&31, row=(reg&3)+8*(reg>>2)+4*(lane>>5)   [verified m74/m101]
// S^T = mfma(K, Q): col = q (fixed per lane), reg axis = keys; regs 0..7 are
// exactly the PV A-slots for keys 4lh+{0-3,8-11}, regs 8..15 for +16. V^T is
// stored with the matching key swizzle so PV B-fragments are single 16B reads.

// ---------------------------------------------------------------- k_prep
// 4 blocks (one per weight) x 512 thr. Coalesced load -> LDS -> transposed
// bf16 write + parallel bias'/u reduction.
__global__ __launch_bounds__(512) void k_prep(
    const float* __restrict__ wq, const float* __restrict__ bq,
    const float* __restrict__ gq, const float* __restrict__ betq,
    const float* __restrict__ wk, const float* __restrict__ bk,
    const float* __restrict__ gk, const float* __restrict__ betk,
    const float* __restrict__ wv, const float* __restrict__ bv,
    const float* __restrict__ gv, const float* __restrict__ betv,
    const float* __restrict__ wp,
    u16* __restrict__ wqT, u16* __restrict__ wkT, u16* __restrict__ wvT, u16* __restrict__ wpT,
    float* __restrict__ bq2, float* __restrict__ bk2, float* __restrict__ bv2,
    float* __restrict__ uq2, float* __restrict__ uk2, float* __restrict__ uv2)
{
  __shared__ float wls[128*129];
  __shared__ float gls[128], bls[128];
  __shared__ float redb[512], redu[512];
  const float ALPHA_Q = 0.17677669529663687f * 1.4426950408889634f; // DH^-0.5 * log2(e)
  int wsel = blockIdx.x, tid = threadIdx.x;
  const float *w, *bb, *g, *bet; u16* wT; float *b2, *u2; float alpha;
  if (wsel == 0){ w=wq; bb=bq; g=gq; bet=betq; wT=wqT; b2=bq2; u2=uq2; alpha=ALPHA_Q; }
  else if (wsel == 1){ w=wk; bb=bk; g=gk; bet=betk; wT=wkT; b2=bk2; u2=uk2; alpha=1.f; }
  else if (wsel == 2){ w=wv; bb=bv; g=gv; bet=betv; wT=wvT; b2=bv2; u2=uv2; alpha=1.f; }
  else { w=wp; bb=nullptr; g=nullptr; bet=nullptr; wT=wpT; b2=nullptr; u2=nullptr; alpha=1.f; }

  if (tid < 128){
    gls[tid] = g ? g[tid] : 1.f;
    bls[tid] = bet ? bet[tid] : 0.f;
  }
  const float4* w4 = (const float4*)w;
  #pragma unroll
  for (int i = 0; i < 8; i++){
    int idx = tid + i*512;              // 4096 float4s
    int row = idx >> 5, c4 = (idx & 31) * 4;   // row = k, c4 = n base
    float4 x = w4[idx];
    wls[row*129 + c4 + 0] = x.x;
    wls[row*129 + c4 + 1] = x.y;
    wls[row*129 + c4 + 2] = x.z;
    wls[row*129 + c4 + 3] = x.w;
  }
  __syncthreads();
  int n = tid >> 2, qp = tid & 3;
  float sb = 0.f, su = 0.f;
  alignas(16) __bf16 tmp[32];
  #pragma unroll
  for (int kk = 0; kk < 32; kk++){
    int k2 = qp*32 + kk;
    float wv_ = wls[k2*129 + n];
    float gv_ = gls[k2];
    sb += bls[k2] * wv_;
    su += gv_ * wv_;
    tmp[kk] = (__bf16)(wv_ * gv_ * alpha);
  }
  #pragma unroll
  for (int j = 0; j < 4; j++)
    *(bf16x8*)(wT + n*128 + qp*32 + j*8) = *(bf16x8*)&tmp[j*8];
  redb[tid] = sb; redu[tid] = su;
  __syncthreads();
  if (qp == 0 && bb){
    float s = bb[n] + redb[tid] + redb[tid+1] + redb[tid+2] + redb[tid+3];
    float u = redu[tid] + redu[tid+1] + redu[tid+2] + redu[tid+3];
    b2[n] = s * alpha;
    u2[n] = u * alpha;
  }
}

// ---------------------------------------------------------------- k_lnproj
// grid 2304 = 128 (b,l) * 6 (n) * 3 (q/k/v); 256 thr (4 waves).
// Raw-x bf16 GEMM; LN applied in epilogue: y = r*z - r*m*u2[n] + b2[n].
// Thread (row=tid>>2, j=tid&3) owns 32 elems of one row: private partial
// sums + 2 shfl_xor in the quad; stats final before the single barrier.
__global__ __launch_bounds__(256) void k_lnproj(
    const float* __restrict__ qg, const float* __restrict__ kg, const float* __restrict__ vg,
    const u16* __restrict__ wqT, const u16* __restrict__ wkT, const u16* __restrict__ wvT,
    const float* __restrict__ bq2, const float* __restrict__ bk2, const float* __restrict__ bv2,
    const float* __restrict__ uq2, const float* __restrict__ uk2, const float* __restrict__ uv2,
    u16* __restrict__ qh, u16* __restrict__ kh, u16* __restrict__ vh)
{
  __shared__ alignas(16) u16 Abf[64*136];
  __shared__ float s1s[64], s2s[64];     // rs / rm
  int bid = blockIdx.x, tid = threadIdx.x;
  int which = bid % 3;
  int t = bid / 3;
  int n = t % 6, bl = t / 6;
  const float* src; const u16* wT; const float *b2, *u2; u16* dstb;
  if (which == 0){ src=qg; wT=wqT; b2=bq2; u2=uq2; dstb=qh; }
  else if (which == 1){ src=kg; wT=wkT; b2=bk2; u2=uk2; dstb=kh; }
  else { src=vg; wT=wvT; b2=bv2; u2=uv2; dstb=vh; }
  int b = bl >> 6, l = bl & 63;
  const float4* s4 = (const float4*)(src + (size_t)((b*6 + n)*64 + l)*64*128);
  int row = tid >> 2, j = tid & 3;
  float s1 = 0.f, s2 = 0.f;
  #pragma unroll
  for (int i = 0; i < 8; i++){
    float4 xv = s4[row*32 + i*4 + j];
    s1 += xv.x + xv.y + xv.z + xv.w;
    s2 += xv.x*xv.x + xv.y*xv.y + xv.z*xv.z + xv.w*xv.w;
    bf16x4 pk;
    pk[0] = (__bf16)xv.x; pk[1] = (__bf16)xv.y;
    pk[2] = (__bf16)xv.z; pk[3] = (__bf16)xv.w;
    *(bf16x4*)&Abf[row*136 + (i*4 + j)*4] = pk;
  }
  s1 += __shfl_xor(s1, 1, 64); s1 += __shfl_xor(s1, 2, 64);
  s2 += __shfl_xor(s2, 1, 64); s2 += __shfl_xor(s2, 2, 64);
  if (j == 0){
    float m = s1 * (1.f/128.f);
    float r = rsqrtf(s2 * (1.f/128.f) - m*m + 1e-5f);
    s1s[row] = r;          // rs
    s2s[row] = r * m;      // rm
  }
  __syncthreads();
  int wave = tid >> 6, lane = tid & 63, lm = lane & 31, lh = lane >> 5;
  bf16x8 bfr[8];
  const u16* wrow = wT + (32*wave + lm)*128 + lh*8;
  #pragma unroll
  for (int ks = 0; ks < 8; ks++) bfr[ks] = *(const bf16x8*)(wrow + ks*16);
  f32x16 acc0, acc1;
  #pragma unroll
  for (int r = 0; r < 16; r++){ acc0[r]=0.f; acc1[r]=0.f; }
  #pragma unroll
  for (int ks = 0; ks < 8; ks++){
    bf16x8 a0 = *(const bf16x8*)&Abf[lm*136       + ks*16 + lh*8];
    bf16x8 a1 = *(const bf16x8*)&Abf[(32+lm)*136  + ks*16 + lh*8];
    acc0 = mfma_bf16(a0, bfr[ks], acc0);
    acc1 = mfma_bf16(a1, bfr[ks], acc1);
  }
  int col = 32*wave + lm;
  float u2c = u2[col], bc = b2[col];
  u16* dst = dstb + ((size_t)(bl*4 + wave)*384 + n*64)*32 + lm;
  #pragma unroll
  for (int r = 0; r < 16; r++){
    int row0 = (r&3) + 8*(r>>2) + 4*lh;
    float y0 = s1s[row0]     * acc0[r] - s2s[row0]     * u2c + bc;
    float y1 = s1s[row0+32]  * acc1[r] - s2s[row0+32]  * u2c + bc;
    *(__bf16*)&dst[(size_t)row0*32]      = (__bf16)y0;
    *(__bf16*)&dst[(size_t)(32+row0)*32] = (__bf16)y1;
  }
}

// ---------------------------------------------------------------- k_attn
// grid 512 = (b,l)*h; 768 thr = 12 waves; wave w: n = w>>1, q-half = w&1.
// K and V^T both staged in LDS in the prologue (all HBM misses overlap);
// inner loop is LDS-only. S^T trick keeps P in registers. LDS 61.9 KB.
__global__ __launch_bounds__(768, 6) void k_attn(
    const u16* __restrict__ qh, const u16* __restrict__ kh, const u16* __restrict__ vh,
    u16* __restrict__ abar)
{
  __shared__ alignas(16) u16 kls[384*36];   // K [key][dh], rows 72 B (pad 4 u16)
  __shared__ alignas(16) u16 vts[32*408];   // V^T [dh][swizzled key], stride 408
  __shared__ float abar_s[64*32];
  int bid = blockIdx.x, tid = threadIdx.x;
  int h = bid & 3, bl = bid >> 2;
  const u16* qb = qh + (size_t)bid * (384*32);
  const u16* kb = kh + (size_t)bid * (384*32);
  const u16* vb = vh + (size_t)bid * (384*32);

  int wave = tid >> 6, lane = tid & 63, lm = lane & 31, lh = lane >> 5;
  int n = wave >> 1, qoff = (wave & 1) * 32;
  int qrow = n*64 + qoff + lm;

  // Q loads first (independent of LDS staging)
  bf16x8 qf0 = *(const bf16x8*)(qb + qrow*32 +      lh*8);
  bf16x8 qf1 = *(const bf16x8*)(qb + qrow*32 + 16 + lh*8);

  // stage K: rows of 32 u16 data in 36-u16 slots; two 8B writes per 16B chunk
  #pragma unroll
  for (int i = 0; i < 2; i++){
    int c = tid + i*768;               // 1536 16B chunks
    int key = c >> 2, part = c & 3;
    U8 kv; kv.u = *(const u16x8*)(kb + key*32 + part*8);
    *(u16x4*)&kls[key*36 + part*8]     = kv.h[0];
    *(u16x4*)&kls[key*36 + part*8 + 4] = kv.h[1];
  }
  // stage V transposed + key-swizzled: key u (mod 32) at a-group perm{0,2,1,3,4,6,5,7}
  #pragma unroll
  for (int i = 0; i < 2; i++){
    int c = tid + i*768;               // 1536 16B chunks
    int key = c >> 2, part = c & 3;
    int u = key & 31, tt = key >> 5;
    int a = u >> 2;
    int anew = (a & 4) | ((a & 1) << 1) | ((a >> 1) & 1);
    int pos = tt*32 + anew*4 + (u & 3);
    u16x8 vv = *(const u16x8*)(vb + key*32 + part*8);
    #pragma unroll
    for (int jj = 0; jj < 8; jj++) vts[(part*8 + jj)*408 + pos] = vv[jj];
  }
  for (int idx = tid; idx < 2048; idx += 768) abar_s[idx] = 0.f;
  __syncthreads();

  const u16* vrow = &vts[lm*408 + 8*lh];
  const u16* krow = &kls[lm*36 + 8*lh];     // + kt*32*36 per tile

  f32x16 oacc;
  #pragma unroll
  for (int r = 0; r < 16; r++) oacc[r] = 0.f;
  float sle = 0.f;

  #pragma unroll
  for (int kt = 0; kt < 12; kt++){
    const u16* kr = krow + kt*(32*36);
    U8 kf0, kf1;
    kf0.h[0] = *(const u16x4*)(kr);         // dh 8lh..8lh+3   (8B, conflict-free)
    kf0.h[1] = *(const u16x4*)(kr + 4);
    kf1.h[0] = *(const u16x4*)(kr + 16);    // dh 16+8lh..
    kf1.h[1] = *(const u16x4*)(kr + 20);
    f32x16 sa, sb_;
    #pragma unroll
    for (int r = 0; r < 16; r++){ sa[r] = 0.f; sb_[r] = 0.f; }
    sa  = mfma_bf16(kf0.b, qf0, sa);        // independent pair
    sb_ = mfma_bf16(kf1.b, qf1, sb_);
    U8 p0, p1;
    #pragma unroll
    for (int r = 0; r < 8; r++){
      float e0 = EXP2(sa[r]   + sb_[r]);
      float e1 = EXP2(sa[r+8] + sb_[r+8]);
      sle += e0 + e1;
      p0.b[r] = (__bf16)e0;                 // v_cvt_pk_bf16_f32 (RNE)
      p1.b[r] = (__bf16)e1;
    }
    U8 v0, v1;
    v0.u = *(const u16x8*)(vrow + kt*32);
    v1.u = *(const u16x8*)(vrow + kt*32 + 16);
    oacc = mfma_bf16(p0.b, v0.b, oacc);
    oacc = mfma_bf16(p1.b, v1.b, oacc);
  }

  // total row sum for q = lm: combine lh halves, then broadcast reciprocals
  sle += __shfl_xor(sle, 32, 64);
  float inv = (1.f/6.f) / sle;

  // oacc lane(lm,lh) reg r = O[q = qoff+(r&3)+8*(r>>2)+4*lh][dh = lm]
  #pragma unroll
  for (int r = 0; r < 16; r++){
    int q_l = (r&3) + 8*(r>>2) + 4*lh;
    float o = oacc[r] * __shfl(inv, q_l, 64);
    atomicAdd(&abar_s[(qoff + q_l)*32 + lm], o);
  }
  __syncthreads();
  u16* ob = abar + (size_t)(bl*64)*128 + h*32;
  for (int idx = tid; idx < 2048; idx += 768){
    int w12 = idx >> 5, dh = idx & 31;
    *(__bf16*)&ob[(size_t)w12*128 + dh] = (__bf16)abar_s[idx];
  }
}

// ---------------------------------------------------------------- k_out
__global__ __launch_bounds__(256) void k_out(
    const u16* __restrict__ abar, const u16* __restrict__ wpT,
    const float* __restrict__ bp, const float* __restrict__ skip,
    float* __restrict__ out)
{
  __shared__ alignas(16) u16 Als[64*136];
  int tid = threadIdx.x;
  int R0 = blockIdx.x * 64;
  #pragma unroll
  for (int i = 0; i < 4; i++){
    int c = tid + i*256;
    int row = c >> 4, part = c & 15;
    *(u16x8*)&Als[row*136 + part*8] = *(const u16x8*)(abar + (size_t)(R0+row)*128 + part*8);
  }
  __syncthreads();
  int wave = tid >> 6, lane = tid & 63, lm = lane & 31, lh = lane >> 5;
  bf16x8 bfr[8];
  const u16* wrow = wpT + (32*wave + lm)*128 + lh*8;
  #pragma unroll
  for (int ks = 0; ks < 8; ks++) bfr[ks] = *(const bf16x8*)(wrow + ks*16);
  f32x16 acc0, acc1;
  #pragma unroll
  for (int r = 0; r < 16; r++){ acc0[r]=0.f; acc1[r]=0.f; }
  #pragma unroll
  for (int ks = 0; ks < 8; ks++){
    bf16x8 a0 = *(const bf16x8*)&Als[lm*136      + ks*16 + lh*8];
    bf16x8 a1 = *(const bf16x8*)&Als[(32+lm)*136 + ks*16 + lh*8];
    acc0 = mfma_bf16(a0, bfr[ks], acc0);
    acc1 = mfma_bf16(a1, bfr[ks], acc1);
  }
  float bias = bp[32*wave + lm];
  #pragma unroll
  for (int r = 0; r < 16; r++){
    int row0 = (r&3) + 8*(r>>2) + 4*lh;
    size_t f0 = (size_t)(R0 + row0)*128 + 32*wave + lm;
    out[f0] = acc0[r] + bias + skip[f0];
    size_t f1 = (size_t)(R0 + 32 + row0)*128 + 32*wave + lm;
    out[f1] = acc1[r] + bias + skip[f1];
  }
}

// ---------------------------------------------------------------- launch
extern "C" void kernel_launch(void* const* d_in, const int* in_sizes, int n_in,
                              void* d_out, int out_size, void* d_ws, size_t ws_size,
                              hipStream_t stream)
{
  const float* q    = (const float*)d_in[0];
  const float* k    = (const float*)d_in[1];
  const float* v    = (const float*)d_in[2];
  const float* skip = (const float*)d_in[3];
  const float* gq   = (const float*)d_in[4];
  const float* betq = (const float*)d_in[5];
  const float* gk   = (const float*)d_in[6];
  const float* betk = (const float*)d_in[7];
  const float* gv   = (const float*)d_in[8];
  const float* betv = (const float*)d_in[9];
  const float* wq   = (const float*)d_in[10];
  const float* bq   = (const float*)d_in[11];
  const float* wk   = (const float*)d_in[12];
  const float* bk   = (const float*)d_in[13];
  const float* wv   = (const float*)d_in[14];
  const float* bv   = (const float*)d_in[15];
  const float* wp   = (const float*)d_in[16];
  const float* bp   = (const float*)d_in[17];
  float* out = (float*)d_out;

  char* ws = (char*)d_ws;
  u16* wqT = (u16*)ws;                 // 16384 u16 each
  u16* wkT = wqT + 16384;
  u16* wvT = wkT + 16384;
  u16* wpT = wvT + 16384;
  float* bq2 = (float*)(ws + 131072);  // 128 f32 each
  float* bk2 = bq2 + 128;
  float* bv2 = bk2 + 128;
  float* uq2 = bv2 + 128;
  float* uk2 = uq2 + 128;
  float* uv2 = uk2 + 128;
  u16* qh = (u16*)(ws + 134144);       // [128][4][384][32] bf16 = 12.58 MB each
  u16* kh = qh + 6291456;
  u16* vh = kh + 6291456;
  u16* abar = vh + 6291456;            // [8192][128] bf16 = 2 MB

  k_prep  <<<4,    512, 0, stream>>>(wq,bq,gq,betq, wk,bk,gk,betk, wv,bv,gv,betv, wp,
                                     wqT,wkT,wvT,wpT, bq2,bk2,bv2, uq2,uk2,uv2);
  k_lnproj<<<2304, 256, 0, stream>>>(q,k,v, wqT,wkT,wvT, bq2,bk2,bv2, uq2,uk2,uv2, qh,kh,vh);
  k_attn  <<<512,  768, 0, stream>>>(qh,kh,vh, abar);
  k_out   <<<128,  256, 0, stream>>>(abar, wpT, bp, skip, out);
}

// Round 6
// 212.788 us; speedup vs baseline: 1.0815x; 1.0018x over previous
//
#include <hip/hip_runtime.h>

// CrossWinAttention on MI355X (gfx950), bf16 MFMA pipeline. R6:
//  - k_attn: hand-unrolled 1-tile-ahead software pipeline with NAMED register
//    sets (A/B alternating via macro). R4's version of this spilled because
//    runtime-indexed local arrays (kf[cur]) land in scratch; named scalars
//    promote cleanly. Next tile's K (ds_read_b64 x4) + V (ds_read_b128 x2)
//    issue before the current tile's exp/PV phase -> LDS latency overlapped
//    by ~240 issue-cycles of softmax work. Watch WRITE_SIZE: ~2 MB = promoted,
//    >>2 MB = scratch (abort path).
//  - k_prep / k_lnproj / k_out unchanged from R5.
//  - Carried: S^T trick (P stays in registers), K+V LDS-staged in prologue,
//    LN folded into GEMM epilogue, mean-over-N folded before final
//    projection, scale*log2e folded into wq/bq (exp2-only softmax),
//    v_exp_f32 + hw bf16 cvt.

typedef unsigned short u16;
typedef __bf16 bf16x8 __attribute__((ext_vector_type(8)));
typedef __bf16 bf16x4 __attribute__((ext_vector_type(4)));
typedef float  f32x16 __attribute__((ext_vector_type(16)));
typedef unsigned short u16x8 __attribute__((ext_vector_type(8)));
typedef unsigned short u16x4 __attribute__((ext_vector_type(4)));

union U8 { u16x8 u; bf16x8 b; u16x4 h[2]; };

#if __has_builtin(__builtin_amdgcn_exp2f)
#define EXP2(x) __builtin_amdgcn_exp2f(x)
#else
#define EXP2(x) exp2f(x)
#endif

__device__ __forceinline__ f32x16 mfma_bf16(bf16x8 a, bf16x8 b, f32x16 c){
  return __builtin_amdgcn_mfma_f32_32x32x16_bf16(a, b, c, 0, 0, 0);
}

// 32x32x16 bf16 fragment conventions:
//  A: m=lane&31, k=(lane>>5)*8+j ; B: n=lane&31, k=(lane>>5)*8+j
//  C/D: col=lane&31, row=(reg&3)+8*(reg>>2)+4*(lane>>5)   [verified m74/m101]
// S^T = mfma(K, Q): col = q (fixed per lane), reg axis = keys; regs 0..7 are
// exactly the PV A-slots for keys 4lh+{0-3,8-11}, regs 8..15 for +16. V^T is
// stored with the matching key swizzle so PV B-fragments are single 16B reads.

// ---------------------------------------------------------------- k_prep
// 4 blocks (one per weight) x 512 thr. Coalesced load -> LDS -> transposed
// bf16 write + parallel bias'/u reduction.
__global__ __launch_bounds__(512) void k_prep(
    const float* __restrict__ wq, const float* __restrict__ bq,
    const float* __restrict__ gq, const float* __restrict__ betq,
    const float* __restrict__ wk, const float* __restrict__ bk,
    const float* __restrict__ gk, const float* __restrict__ betk,
    const float* __restrict__ wv, const float* __restrict__ bv,
    const float* __restrict__ gv, const float* __restrict__ betv,
    const float* __restrict__ wp,
    u16* __restrict__ wqT, u16* __restrict__ wkT, u16* __restrict__ wvT, u16* __restrict__ wpT,
    float* __restrict__ bq2, float* __restrict__ bk2, float* __restrict__ bv2,
    float* __restrict__ uq2, float* __restrict__ uk2, float* __restrict__ uv2)
{
  __shared__ float wls[128*129];
  __shared__ float gls[128], bls[128];
  __shared__ float redb[512], redu[512];
  const float ALPHA_Q = 0.17677669529663687f * 1.4426950408889634f; // DH^-0.5 * log2(e)
  int wsel = blockIdx.x, tid = threadIdx.x;
  const float *w, *bb, *g, *bet; u16* wT; float *b2, *u2; float alpha;
  if (wsel == 0){ w=wq; bb=bq; g=gq; bet=betq; wT=wqT; b2=bq2; u2=uq2; alpha=ALPHA_Q; }
  else if (wsel == 1){ w=wk; bb=bk; g=gk; bet=betk; wT=wkT; b2=bk2; u2=uk2; alpha=1.f; }
  else if (wsel == 2){ w=wv; bb=bv; g=gv; bet=betv; wT=wvT; b2=bv2; u2=uv2; alpha=1.f; }
  else { w=wp; bb=nullptr; g=nullptr; bet=nullptr; wT=wpT; b2=nullptr; u2=nullptr; alpha=1.f; }

  if (tid < 128){
    gls[tid] = g ? g[tid] : 1.f;
    bls[tid] = bet ? bet[tid] : 0.f;
  }
  const float4* w4 = (const float4*)w;
  #pragma unroll
  for (int i = 0; i < 8; i++){
    int idx = tid + i*512;              // 4096 float4s
    int row = idx >> 5, c4 = (idx & 31) * 4;   // row = k, c4 = n base
    float4 x = w4[idx];
    wls[row*129 + c4 + 0] = x.x;
    wls[row*129 + c4 + 1] = x.y;
    wls[row*129 + c4 + 2] = x.z;
    wls[row*129 + c4 + 3] = x.w;
  }
  __syncthreads();
  int n = tid >> 2, qp = tid & 3;
  float sb = 0.f, su = 0.f;
  alignas(16) __bf16 tmp[32];
  #pragma unroll
  for (int kk = 0; kk < 32; kk++){
    int k2 = qp*32 + kk;
    float wv_ = wls[k2*129 + n];
    float gv_ = gls[k2];
    sb += bls[k2] * wv_;
    su += gv_ * wv_;
    tmp[kk] = (__bf16)(wv_ * gv_ * alpha);
  }
  #pragma unroll
  for (int j = 0; j < 4; j++)
    *(bf16x8*)(wT + n*128 + qp*32 + j*8) = *(bf16x8*)&tmp[j*8];
  redb[tid] = sb; redu[tid] = su;
  __syncthreads();
  if (qp == 0 && bb){
    float s = bb[n] + redb[tid] + redb[tid+1] + redb[tid+2] + redb[tid+3];
    float u = redu[tid] + redu[tid+1] + redu[tid+2] + redu[tid+3];
    b2[n] = s * alpha;
    u2[n] = u * alpha;
  }
}

// ---------------------------------------------------------------- k_lnproj
// grid 2304 = 128 (b,l) * 6 (n) * 3 (q/k/v); 256 thr (4 waves).
// Raw-x bf16 GEMM; LN applied in epilogue: y = r*z - r*m*u2[n] + b2[n].
__global__ __launch_bounds__(256) void k_lnproj(
    const float* __restrict__ qg, const float* __restrict__ kg, const float* __restrict__ vg,
    const u16* __restrict__ wqT, const u16* __restrict__ wkT, const u16* __restrict__ wvT,
    const float* __restrict__ bq2, const float* __restrict__ bk2, const float* __restrict__ bv2,
    const float* __restrict__ uq2, const float* __restrict__ uk2, const float* __restrict__ uv2,
    u16* __restrict__ qh, u16* __restrict__ kh, u16* __restrict__ vh)
{
  __shared__ alignas(16) u16 Abf[64*136];
  __shared__ float s1s[64], s2s[64];     // rs / rm
  int bid = blockIdx.x, tid = threadIdx.x;
  int which = bid % 3;
  int t = bid / 3;
  int n = t % 6, bl = t / 6;
  const float* src; const u16* wT; const float *b2, *u2; u16* dstb;
  if (which == 0){ src=qg; wT=wqT; b2=bq2; u2=uq2; dstb=qh; }
  else if (which == 1){ src=kg; wT=wkT; b2=bk2; u2=uk2; dstb=kh; }
  else { src=vg; wT=wvT; b2=bv2; u2=uv2; dstb=vh; }
  int b = bl >> 6, l = bl & 63;
  const float4* s4 = (const float4*)(src + (size_t)((b*6 + n)*64 + l)*64*128);
  int row = tid >> 2, j = tid & 3;
  float s1 = 0.f, s2 = 0.f;
  #pragma unroll
  for (int i = 0; i < 8; i++){
    float4 xv = s4[row*32 + i*4 + j];
    s1 += xv.x + xv.y + xv.z + xv.w;
    s2 += xv.x*xv.x + xv.y*xv.y + xv.z*xv.z + xv.w*xv.w;
    bf16x4 pk;
    pk[0] = (__bf16)xv.x; pk[1] = (__bf16)xv.y;
    pk[2] = (__bf16)xv.z; pk[3] = (__bf16)xv.w;
    *(bf16x4*)&Abf[row*136 + (i*4 + j)*4] = pk;
  }
  s1 += __shfl_xor(s1, 1, 64); s1 += __shfl_xor(s1, 2, 64);
  s2 += __shfl_xor(s2, 1, 64); s2 += __shfl_xor(s2, 2, 64);
  if (j == 0){
    float m = s1 * (1.f/128.f);
    float r = rsqrtf(s2 * (1.f/128.f) - m*m + 1e-5f);
    s1s[row] = r;          // rs
    s2s[row] = r * m;      // rm
  }
  __syncthreads();
  int wave = tid >> 6, lane = tid & 63, lm = lane & 31, lh = lane >> 5;
  bf16x8 bfr[8];
  const u16* wrow = wT + (32*wave + lm)*128 + lh*8;
  #pragma unroll
  for (int ks = 0; ks < 8; ks++) bfr[ks] = *(const bf16x8*)(wrow + ks*16);
  f32x16 acc0, acc1;
  #pragma unroll
  for (int r = 0; r < 16; r++){ acc0[r]=0.f; acc1[r]=0.f; }
  #pragma unroll
  for (int ks = 0; ks < 8; ks++){
    bf16x8 a0 = *(const bf16x8*)&Abf[lm*136       + ks*16 + lh*8];
    bf16x8 a1 = *(const bf16x8*)&Abf[(32+lm)*136  + ks*16 + lh*8];
    acc0 = mfma_bf16(a0, bfr[ks], acc0);
    acc1 = mfma_bf16(a1, bfr[ks], acc1);
  }
  int col = 32*wave + lm;
  float u2c = u2[col], bc = b2[col];
  u16* dst = dstb + ((size_t)(bl*4 + wave)*384 + n*64)*32 + lm;
  #pragma unroll
  for (int r = 0; r < 16; r++){
    int row0 = (r&3) + 8*(r>>2) + 4*lh;
    float y0 = s1s[row0]     * acc0[r] - s2s[row0]     * u2c + bc;
    float y1 = s1s[row0+32]  * acc1[r] - s2s[row0+32]  * u2c + bc;
    *(__bf16*)&dst[(size_t)row0*32]      = (__bf16)y0;
    *(__bf16*)&dst[(size_t)(32+row0)*32] = (__bf16)y1;
  }
}

// ---------------------------------------------------------------- k_attn
// grid 512 = (b,l)*h; 768 thr = 12 waves; wave w: n = w>>1, q-half = w&1.
// K and V^T LDS-staged in prologue; inner loop = hand-unrolled 1-ahead
// pipeline with named A/B register sets (no runtime-indexed arrays).
__global__ __launch_bounds__(768) void k_attn(
    const u16* __restrict__ qh, const u16* __restrict__ kh, const u16* __restrict__ vh,
    u16* __restrict__ abar)
{
  __shared__ alignas(16) u16 kls[384*36];   // K [key][dh], rows 72 B (pad 4 u16)
  __shared__ alignas(16) u16 vts[32*408];   // V^T [dh][swizzled key], stride 408
  __shared__ float abar_s[64*32];
  int bid = blockIdx.x, tid = threadIdx.x;
  int h = bid & 3, bl = bid >> 2;
  const u16* qb = qh + (size_t)bid * (384*32);
  const u16* kb = kh + (size_t)bid * (384*32);
  const u16* vb = vh + (size_t)bid * (384*32);

  int wave = tid >> 6, lane = tid & 63, lm = lane & 31, lh = lane >> 5;
  int n = wave >> 1, qoff = (wave & 1) * 32;
  int qrow = n*64 + qoff + lm;

  // Q loads first (independent of LDS staging)
  bf16x8 qf0 = *(const bf16x8*)(qb + qrow*32 +      lh*8);
  bf16x8 qf1 = *(const bf16x8*)(qb + qrow*32 + 16 + lh*8);

  // stage K: rows of 32 u16 data in 36-u16 slots; two 8B writes per 16B chunk
  #pragma unroll
  for (int i = 0; i < 2; i++){
    int c = tid + i*768;               // 1536 16B chunks
    int key = c >> 2, part = c & 3;
    U8 kv; kv.u = *(const u16x8*)(kb + key*32 + part*8);
    *(u16x4*)&kls[key*36 + part*8]     = kv.h[0];
    *(u16x4*)&kls[key*36 + part*8 + 4] = kv.h[1];
  }
  // stage V transposed + key-swizzled: key u (mod 32) at a-group perm{0,2,1,3,4,6,5,7}
  #pragma unroll
  for (int i = 0; i < 2; i++){
    int c = tid + i*768;               // 1536 16B chunks
    int key = c >> 2, part = c & 3;
    int u = key & 31, tt = key >> 5;
    int a = u >> 2;
    int anew = (a & 4) | ((a & 1) << 1) | ((a >> 1) & 1);
    int pos = tt*32 + anew*4 + (u & 3);
    u16x8 vv = *(const u16x8*)(vb + key*32 + part*8);
    #pragma unroll
    for (int jj = 0; jj < 8; jj++) vts[(part*8 + jj)*408 + pos] = vv[jj];
  }
  for (int idx = tid; idx < 2048; idx += 768) abar_s[idx] = 0.f;
  __syncthreads();

  const u16* vrow = &vts[lm*408 + 8*lh];
  const u16* krow = &kls[lm*36 + 8*lh];     // + kt*32*36 per tile

  f32x16 oacc;
  #pragma unroll
  for (int r = 0; r < 16; r++) oacc[r] = 0.f;
  float sle = 0.f;

  // named A/B register sets for the 1-ahead pipeline
  U8 Ak0, Ak1, Bk0, Bk1;
  U8 Av0, Av1, Bv0, Bv1;

  // prime tile 0 into the A set
  Ak0.h[0] = *(const u16x4*)(krow);       Ak0.h[1] = *(const u16x4*)(krow + 4);
  Ak1.h[0] = *(const u16x4*)(krow + 16);  Ak1.h[1] = *(const u16x4*)(krow + 20);
  Av0.u = *(const u16x8*)(vrow);
  Av1.u = *(const u16x8*)(vrow + 16);

#define ATTN_TILE(CK0, CK1, CV0, CV1, NK0, NK1, NV0, NV1, KT)                  \
  do {                                                                         \
    if ((KT) < 11){                                                            \
      const u16* kr_ = krow + ((KT)+1)*(32*36);                                \
      NK0.h[0] = *(const u16x4*)(kr_);      NK0.h[1] = *(const u16x4*)(kr_+4); \
      NK1.h[0] = *(const u16x4*)(kr_+16);   NK1.h[1] = *(const u16x4*)(kr_+20);\
      NV0.u = *(const u16x8*)(vrow + ((KT)+1)*32);                             \
      NV1.u = *(const u16x8*)(vrow + ((KT)+1)*32 + 16);                        \
    }                                                                          \
    f32x16 sa_, sb_;                                                           \
    _Pragma("unroll")                                                          \
    for (int r = 0; r < 16; r++){ sa_[r] = 0.f; sb_[r] = 0.f; }                \
    sa_ = mfma_bf16(CK0.b, qf0, sa_);                                          \
    sb_ = mfma_bf16(CK1.b, qf1, sb_);                                          \
    U8 p0_, p1_;                                                               \
    _Pragma("unroll")                                                          \
    for (int r = 0; r < 8; r++){                                               \
      float e0 = EXP2(sa_[r]   + sb_[r]);                                      \
      float e1 = EXP2(sa_[r+8] + sb_[r+8]);                                    \
      sle += e0 + e1;                                                          \
      p0_.b[r] = (__bf16)e0;                                                   \
      p1_.b[r] = (__bf16)e1;                                                   \
    }                                                                          \
    oacc = mfma_bf16(p0_.b, CV0.b, oacc);                                      \
    oacc = mfma_bf16(p1_.b, CV1.b, oacc);                                      \
  } while (0)

  ATTN_TILE(Ak0, Ak1, Av0, Av1, Bk0, Bk1, Bv0, Bv1, 0);
  ATTN_TILE(Bk0, Bk1, Bv0, Bv1, Ak0, Ak1, Av0, Av1, 1);
  ATTN_TILE(Ak0, Ak1, Av0, Av1, Bk0, Bk1, Bv0, Bv1, 2);
  ATTN_TILE(Bk0, Bk1, Bv0, Bv1, Ak0, Ak1, Av0, Av1, 3);
  ATTN_TILE(Ak0, Ak1, Av0, Av1, Bk0, Bk1, Bv0, Bv1, 4);
  ATTN_TILE(Bk0, Bk1, Bv0, Bv1, Ak0, Ak1, Av0, Av1, 5);
  ATTN_TILE(Ak0, Ak1, Av0, Av1, Bk0, Bk1, Bv0, Bv1, 6);
  ATTN_TILE(Bk0, Bk1, Bv0, Bv1, Ak0, Ak1, Av0, Av1, 7);
  ATTN_TILE(Ak0, Ak1, Av0, Av1, Bk0, Bk1, Bv0, Bv1, 8);
  ATTN_TILE(Bk0, Bk1, Bv0, Bv1, Ak0, Ak1, Av0, Av1, 9);
  ATTN_TILE(Ak0, Ak1, Av0, Av1, Bk0, Bk1, Bv0, Bv1, 10);
  ATTN_TILE(Bk0, Bk1, Bv0, Bv1, Ak0, Ak1, Av0, Av1, 11);
#undef ATTN_TILE

  // total row sum for q = lm: combine lh halves, then broadcast reciprocals
  sle += __shfl_xor(sle, 32, 64);
  float inv = (1.f/6.f) / sle;

  // oacc lane(lm,lh) reg r = O[q = qoff+(r&3)+8*(r>>2)+4*lh][dh = lm]
  #pragma unroll
  for (int r = 0; r < 16; r++){
    int q_l = (r&3) + 8*(r>>2) + 4*lh;
    float o = oacc[r] * __shfl(inv, q_l, 64);
    atomicAdd(&abar_s[(qoff + q_l)*32 + lm], o);
  }
  __syncthreads();
  u16* ob = abar + (size_t)(bl*64)*128 + h*32;
  for (int idx = tid; idx < 2048; idx += 768){
    int w12 = idx >> 5, dh = idx & 31;
    *(__bf16*)&ob[(size_t)w12*128 + dh] = (__bf16)abar_s[idx];
  }
}

// ---------------------------------------------------------------- k_out
__global__ __launch_bounds__(256) void k_out(
    const u16* __restrict__ abar, const u16* __restrict__ wpT,
    const float* __restrict__ bp, const float* __restrict__ skip,
    float* __restrict__ out)
{
  __shared__ alignas(16) u16 Als[64*136];
  int tid = threadIdx.x;
  int R0 = blockIdx.x * 64;
  #pragma unroll
  for (int i = 0; i < 4; i++){
    int c = tid + i*256;
    int row = c >> 4, part = c & 15;
    *(u16x8*)&Als[row*136 + part*8] = *(const u16x8*)(abar + (size_t)(R0+row)*128 + part*8);
  }
  __syncthreads();
  int wave = tid >> 6, lane = tid & 63, lm = lane & 31, lh = lane >> 5;
  bf16x8 bfr[8];
  const u16* wrow = wpT + (32*wave + lm)*128 + lh*8;
  #pragma unroll
  for (int ks = 0; ks < 8; ks++) bfr[ks] = *(const bf16x8*)(wrow + ks*16);
  f32x16 acc0, acc1;
  #pragma unroll
  for (int r = 0; r < 16; r++){ acc0[r]=0.f; acc1[r]=0.f; }
  #pragma unroll
  for (int ks = 0; ks < 8; ks++){
    bf16x8 a0 = *(const bf16x8*)&Als[lm*136      + ks*16 + lh*8];
    bf16x8 a1 = *(const bf16x8*)&Als[(32+lm)*136 + ks*16 + lh*8];
    acc0 = mfma_bf16(a0, bfr[ks], acc0);
    acc1 = mfma_bf16(a1, bfr[ks], acc1);
  }
  float bias = bp[32*wave + lm];
  #pragma unroll
  for (int r = 0; r < 16; r++){
    int row0 = (r&3) + 8*(r>>2) + 4*lh;
    size_t f0 = (size_t)(R0 + row0)*128 + 32*wave + lm;
    out[f0] = acc0[r] + bias + skip[f0];
    size_t f1 = (size_t)(R0 + 32 + row0)*128 + 32*wave + lm;
    out[f1] = acc1[r] + bias + skip[f1];
  }
}

// ---------------------------------------------------------------- launch
extern "C" void kernel_launch(void* const* d_in, const int* in_sizes, int n_in,
                              void* d_out, int out_size, void* d_ws, size_t ws_size,
                              hipStream_t stream)
{
  const float* q    = (const float*)d_in[0];
  const float* k    = (const float*)d_in[1];
  const float* v    = (const float*)d_in[2];
  const float* skip = (const float*)d_in[3];
  const float* gq   = (const float*)d_in[4];
  const float* betq = (const float*)d_in[5];
  const float* gk   = (const float*)d_in[6];
  const float* betk = (const float*)d_in[7];
  const float* gv   = (const float*)d_in[8];
  const float* betv = (const float*)d_in[9];
  const float* wq   = (const float*)d_in[10];
  const float* bq   = (const float*)d_in[11];
  const float* wk   = (const float*)d_in[12];
  const float* bk   = (const float*)d_in[13];
  const float* wv   = (const float*)d_in[14];
  const float* bv   = (const float*)d_in[15];
  const float* wp   = (const float*)d_in[16];
  const float* bp   = (const float*)d_in[17];
  float* out = (float*)d_out;

  char* ws = (char*)d_ws;
  u16* wqT = (u16*)ws;                 // 16384 u16 each
  u16* wkT = wqT + 16384;
  u16* wvT = wkT + 16384;
  u16* wpT = wvT + 16384;
  float* bq2 = (float*)(ws + 131072);  // 128 f32 each
  float* bk2 = bq2 + 128;
  float* bv2 = bk2 + 128;
  float* uq2 = bv2 + 128;
  float* uk2 = uq2 + 128;
  float* uv2 = uk2 + 128;
  u16* qh = (u16*)(ws + 134144);       // [128][4][384][32] bf16 = 12.58 MB each
  u16* kh = qh + 6291456;
  u16* vh = kh + 6291456;
  u16* abar = vh + 6291456;            // [8192][128] bf16 = 2 MB

  k_prep  <<<4,    512, 0, stream>>>(wq,bq,gq,betq, wk,bk,gk,betk, wv,bv,gv,betv, wp,
                                     wqT,wkT,wvT,wpT, bq2,bk2,bv2, uq2,uk2,uv2);
  k_lnproj<<<2304, 256, 0, stream>>>(q,k,v, wqT,wkT,wvT, bq2,bk2,bv2, uq2,uk2,uv2, qh,kh,vh);
  k_attn  <<<512,  768, 0, stream>>>(qh,kh,vh, abar);
  k_out   <<<128,  256, 0, stream>>>(abar, wpT, bp, skip, out);
}

// Round 7
// 210.449 us; speedup vs baseline: 1.0935x; 1.0111x over previous
//
#include <hip/hip_runtime.h>

// CrossWinAttention on MI355X (gfx950), bf16 MFMA pipeline. R7:
//  - k_attn restructured: block = 384 thr (6 waves), each wave owns a FULL n
//    (64 q rows = two q-groups A/B). Two independent S-chains + 32 independent
//    exp2 + 8 MFMAs per tile = ~2x ILP per chain step vs R6. K read from
//    global (R3-style; LDS-staging K proved neutral), so LDS drops 62->34.3 KB
//    -> 3 blocks/CU possible. Full unroll, no intra-loop barriers: LLVM
//    schedules/hoists loads itself (R6 showed no spill without a reg cap;
//    watch WRITE_SIZE ~2 MB as the no-scratch check).
//  - k_prep / k_lnproj / k_out unchanged.
//  - Carried: S^T trick (P stays in registers), V^T key-swizzled in LDS,
//    LN folded into GEMM epilogue, mean-over-N folded before final
//    projection, scale*log2e folded into wq/bq (exp2-only softmax),
//    v_exp_f32 + hw bf16 cvt.

typedef unsigned short u16;
typedef __bf16 bf16x8 __attribute__((ext_vector_type(8)));
typedef __bf16 bf16x4 __attribute__((ext_vector_type(4)));
typedef float  f32x16 __attribute__((ext_vector_type(16)));
typedef unsigned short u16x8 __attribute__((ext_vector_type(8)));
typedef unsigned short u16x4 __attribute__((ext_vector_type(4)));

union U8 { u16x8 u; bf16x8 b; u16x4 h[2]; };

#if __has_builtin(__builtin_amdgcn_exp2f)
#define EXP2(x) __builtin_amdgcn_exp2f(x)
#else
#define EXP2(x) exp2f(x)
#endif

__device__ __forceinline__ f32x16 mfma_bf16(bf16x8 a, bf16x8 b, f32x16 c){
  return __builtin_amdgcn_mfma_f32_32x32x16_bf16(a, b, c, 0, 0, 0);
}

// 32x32x16 bf16 fragment conventions:
//  A: m=lane&31, k=(lane>>5)*8+j ; B: n=lane&31, k=(lane>>5)*8+j
//  C/D: col=lane&31, row=(reg&3)+8*(reg>>2)+4*(lane>>5)   [verified m74/m101]
// S^T = mfma(K, Q): col = q (fixed per lane), reg axis = keys; regs 0..7 are
// exactly the PV A-slots for keys 4lh+{0-3,8-11}, regs 8..15 for +16. V^T is
// stored with the matching key swizzle so PV B-fragments are single 16B reads.

// ---------------------------------------------------------------- k_prep
// 4 blocks (one per weight) x 512 thr. Coalesced load -> LDS -> transposed
// bf16 write + parallel bias'/u reduction.
__global__ __launch_bounds__(512) void k_prep(
    const float* __restrict__ wq, const float* __restrict__ bq,
    const float* __restrict__ gq, const float* __restrict__ betq,
    const float* __restrict__ wk, const float* __restrict__ bk,
    const float* __restrict__ gk, const float* __restrict__ betk,
    const float* __restrict__ wv, const float* __restrict__ bv,
    const float* __restrict__ gv, const float* __restrict__ betv,
    const float* __restrict__ wp,
    u16* __restrict__ wqT, u16* __restrict__ wkT, u16* __restrict__ wvT, u16* __restrict__ wpT,
    float* __restrict__ bq2, float* __restrict__ bk2, float* __restrict__ bv2,
    float* __restrict__ uq2, float* __restrict__ uk2, float* __restrict__ uv2)
{
  __shared__ float wls[128*129];
  __shared__ float gls[128], bls[128];
  __shared__ float redb[512], redu[512];
  const float ALPHA_Q = 0.17677669529663687f * 1.4426950408889634f; // DH^-0.5 * log2(e)
  int wsel = blockIdx.x, tid = threadIdx.x;
  const float *w, *bb, *g, *bet; u16* wT; float *b2, *u2; float alpha;
  if (wsel == 0){ w=wq; bb=bq; g=gq; bet=betq; wT=wqT; b2=bq2; u2=uq2; alpha=ALPHA_Q; }
  else if (wsel == 1){ w=wk; bb=bk; g=gk; bet=betk; wT=wkT; b2=bk2; u2=uk2; alpha=1.f; }
  else if (wsel == 2){ w=wv; bb=bv; g=gv; bet=betv; wT=wvT; b2=bv2; u2=uv2; alpha=1.f; }
  else { w=wp; bb=nullptr; g=nullptr; bet=nullptr; wT=wpT; b2=nullptr; u2=nullptr; alpha=1.f; }

  if (tid < 128){
    gls[tid] = g ? g[tid] : 1.f;
    bls[tid] = bet ? bet[tid] : 0.f;
  }
  const float4* w4 = (const float4*)w;
  #pragma unroll
  for (int i = 0; i < 8; i++){
    int idx = tid + i*512;              // 4096 float4s
    int row = idx >> 5, c4 = (idx & 31) * 4;   // row = k, c4 = n base
    float4 x = w4[idx];
    wls[row*129 + c4 + 0] = x.x;
    wls[row*129 + c4 + 1] = x.y;
    wls[row*129 + c4 + 2] = x.z;
    wls[row*129 + c4 + 3] = x.w;
  }
  __syncthreads();
  int n = tid >> 2, qp = tid & 3;
  float sb = 0.f, su = 0.f;
  alignas(16) __bf16 tmp[32];
  #pragma unroll
  for (int kk = 0; kk < 32; kk++){
    int k2 = qp*32 + kk;
    float wv_ = wls[k2*129 + n];
    float gv_ = gls[k2];
    sb += bls[k2] * wv_;
    su += gv_ * wv_;
    tmp[kk] = (__bf16)(wv_ * gv_ * alpha);
  }
  #pragma unroll
  for (int j = 0; j < 4; j++)
    *(bf16x8*)(wT + n*128 + qp*32 + j*8) = *(bf16x8*)&tmp[j*8];
  redb[tid] = sb; redu[tid] = su;
  __syncthreads();
  if (qp == 0 && bb){
    float s = bb[n] + redb[tid] + redb[tid+1] + redb[tid+2] + redb[tid+3];
    float u = redu[tid] + redu[tid+1] + redu[tid+2] + redu[tid+3];
    b2[n] = s * alpha;
    u2[n] = u * alpha;
  }
}

// ---------------------------------------------------------------- k_lnproj
// grid 2304 = 128 (b,l) * 6 (n) * 3 (q/k/v); 256 thr (4 waves).
// Raw-x bf16 GEMM; LN applied in epilogue: y = r*z - r*m*u2[n] + b2[n].
__global__ __launch_bounds__(256) void k_lnproj(
    const float* __restrict__ qg, const float* __restrict__ kg, const float* __restrict__ vg,
    const u16* __restrict__ wqT, const u16* __restrict__ wkT, const u16* __restrict__ wvT,
    const float* __restrict__ bq2, const float* __restrict__ bk2, const float* __restrict__ bv2,
    const float* __restrict__ uq2, const float* __restrict__ uk2, const float* __restrict__ uv2,
    u16* __restrict__ qh, u16* __restrict__ kh, u16* __restrict__ vh)
{
  __shared__ alignas(16) u16 Abf[64*136];
  __shared__ float s1s[64], s2s[64];     // rs / rm
  int bid = blockIdx.x, tid = threadIdx.x;
  int which = bid % 3;
  int t = bid / 3;
  int n = t % 6, bl = t / 6;
  const float* src; const u16* wT; const float *b2, *u2; u16* dstb;
  if (which == 0){ src=qg; wT=wqT; b2=bq2; u2=uq2; dstb=qh; }
  else if (which == 1){ src=kg; wT=wkT; b2=bk2; u2=uk2; dstb=kh; }
  else { src=vg; wT=wvT; b2=bv2; u2=uv2; dstb=vh; }
  int b = bl >> 6, l = bl & 63;
  const float4* s4 = (const float4*)(src + (size_t)((b*6 + n)*64 + l)*64*128);
  int row = tid >> 2, j = tid & 3;
  float s1 = 0.f, s2 = 0.f;
  #pragma unroll
  for (int i = 0; i < 8; i++){
    float4 xv = s4[row*32 + i*4 + j];
    s1 += xv.x + xv.y + xv.z + xv.w;
    s2 += xv.x*xv.x + xv.y*xv.y + xv.z*xv.z + xv.w*xv.w;
    bf16x4 pk;
    pk[0] = (__bf16)xv.x; pk[1] = (__bf16)xv.y;
    pk[2] = (__bf16)xv.z; pk[3] = (__bf16)xv.w;
    *(bf16x4*)&Abf[row*136 + (i*4 + j)*4] = pk;
  }
  s1 += __shfl_xor(s1, 1, 64); s1 += __shfl_xor(s1, 2, 64);
  s2 += __shfl_xor(s2, 1, 64); s2 += __shfl_xor(s2, 2, 64);
  if (j == 0){
    float m = s1 * (1.f/128.f);
    float r = rsqrtf(s2 * (1.f/128.f) - m*m + 1e-5f);
    s1s[row] = r;          // rs
    s2s[row] = r * m;      // rm
  }
  __syncthreads();
  int wave = tid >> 6, lane = tid & 63, lm = lane & 31, lh = lane >> 5;
  bf16x8 bfr[8];
  const u16* wrow = wT + (32*wave + lm)*128 + lh*8;
  #pragma unroll
  for (int ks = 0; ks < 8; ks++) bfr[ks] = *(const bf16x8*)(wrow + ks*16);
  f32x16 acc0, acc1;
  #pragma unroll
  for (int r = 0; r < 16; r++){ acc0[r]=0.f; acc1[r]=0.f; }
  #pragma unroll
  for (int ks = 0; ks < 8; ks++){
    bf16x8 a0 = *(const bf16x8*)&Abf[lm*136       + ks*16 + lh*8];
    bf16x8 a1 = *(const bf16x8*)&Abf[(32+lm)*136  + ks*16 + lh*8];
    acc0 = mfma_bf16(a0, bfr[ks], acc0);
    acc1 = mfma_bf16(a1, bfr[ks], acc1);
  }
  int col = 32*wave + lm;
  float u2c = u2[col], bc = b2[col];
  u16* dst = dstb + ((size_t)(bl*4 + wave)*384 + n*64)*32 + lm;
  #pragma unroll
  for (int r = 0; r < 16; r++){
    int row0 = (r&3) + 8*(r>>2) + 4*lh;
    float y0 = s1s[row0]     * acc0[r] - s2s[row0]     * u2c + bc;
    float y1 = s1s[row0+32]  * acc1[r] - s2s[row0+32]  * u2c + bc;
    *(__bf16*)&dst[(size_t)row0*32]      = (__bf16)y0;
    *(__bf16*)&dst[(size_t)(32+row0)*32] = (__bf16)y1;
  }
}

// ---------------------------------------------------------------- k_attn
// grid 512 = (b,l)*h; 384 thr = 6 waves; wave w = n (owns all 64 q rows of
// its view: q-groups A = rows 0-31, B = rows 32-63 within the n-chunk).
// K from global; V^T key-swizzled in LDS. LDS 34.3 KB.
__global__ __launch_bounds__(384) void k_attn(
    const u16* __restrict__ qh, const u16* __restrict__ kh, const u16* __restrict__ vh,
    u16* __restrict__ abar)
{
  __shared__ alignas(16) u16 vts[32*408];   // V^T [dh][swizzled key], stride 408
  __shared__ float abar_s[64*32];
  int bid = blockIdx.x, tid = threadIdx.x;
  int h = bid & 3, bl = bid >> 2;
  const u16* qb = qh + (size_t)bid * (384*32);
  const u16* kb = kh + (size_t)bid * (384*32);
  const u16* vb = vh + (size_t)bid * (384*32);

  int wave = tid >> 6, lane = tid & 63, lm = lane & 31, lh = lane >> 5;
  int n = wave;                       // 6 waves == 6 views

  // Q fragments: group A = q rows n*64+lm, group B = +32 (independent of LDS)
  const u16* qbase = qb + (size_t)(n*64 + lm)*32 + lh*8;
  bf16x8 qfA0 = *(const bf16x8*)(qbase);
  bf16x8 qfA1 = *(const bf16x8*)(qbase + 16);
  bf16x8 qfB0 = *(const bf16x8*)(qbase + 32*32);
  bf16x8 qfB1 = *(const bf16x8*)(qbase + 32*32 + 16);

  // stage V transposed + key-swizzled: key u (mod 32) at a-group perm{0,2,1,3,4,6,5,7}
  #pragma unroll
  for (int i = 0; i < 4; i++){
    int c = tid + i*384;               // 1536 16B chunks
    int key = c >> 2, part = c & 3;
    int u = key & 31, tt = key >> 5;
    int a = u >> 2;
    int anew = (a & 4) | ((a & 1) << 1) | ((a >> 1) & 1);
    int pos = tt*32 + anew*4 + (u & 3);
    u16x8 vv = *(const u16x8*)(vb + key*32 + part*8);
    #pragma unroll
    for (int jj = 0; jj < 8; jj++) vts[(part*8 + jj)*408 + pos] = vv[jj];
  }
  for (int idx = tid; idx < 2048; idx += 384) abar_s[idx] = 0.f;
  __syncthreads();

  const u16* vrow = &vts[lm*408 + 8*lh];
  const u16* krow = kb + lm*32 + lh*8;

  f32x16 oA, oB;
  #pragma unroll
  for (int r = 0; r < 16; r++){ oA[r] = 0.f; oB[r] = 0.f; }
  float sleA = 0.f, sleB = 0.f;

  #pragma unroll
  for (int kt = 0; kt < 12; kt++){
    bf16x8 kf0 = *(const bf16x8*)(krow + kt*(32*32));
    bf16x8 kf1 = *(const bf16x8*)(krow + kt*(32*32) + 16);
    f32x16 sa, sb_;
    #pragma unroll
    for (int r = 0; r < 16; r++){ sa[r] = 0.f; sb_[r] = 0.f; }
    sa  = mfma_bf16(kf0, qfA0, sa);      // two independent chains (A/B)
    sb_ = mfma_bf16(kf0, qfB0, sb_);
    sa  = mfma_bf16(kf1, qfA1, sa);
    sb_ = mfma_bf16(kf1, qfB1, sb_);
    U8 v0, v1;
    v0.u = *(const u16x8*)(vrow + kt*32);
    v1.u = *(const u16x8*)(vrow + kt*32 + 16);
    U8 pA0, pA1, pB0, pB1;
    #pragma unroll
    for (int r = 0; r < 8; r++){
      float eA0 = EXP2(sa[r]);
      float eA1 = EXP2(sa[r+8]);
      float eB0 = EXP2(sb_[r]);
      float eB1 = EXP2(sb_[r+8]);
      sleA += eA0 + eA1;
      sleB += eB0 + eB1;
      pA0.b[r] = (__bf16)eA0;            // v_cvt_pk_bf16_f32 (RNE)
      pA1.b[r] = (__bf16)eA1;
      pB0.b[r] = (__bf16)eB0;
      pB1.b[r] = (__bf16)eB1;
    }
    oA = mfma_bf16(pA0.b, v0.b, oA);
    oB = mfma_bf16(pB0.b, v0.b, oB);
    oA = mfma_bf16(pA1.b, v1.b, oA);
    oB = mfma_bf16(pB1.b, v1.b, oB);
  }

  // row sums: combine lh halves, broadcast reciprocals (1/6 = mean over n)
  sleA += __shfl_xor(sleA, 32, 64);
  sleB += __shfl_xor(sleB, 32, 64);
  float invA = (1.f/6.f) / sleA;
  float invB = (1.f/6.f) / sleB;

  // o lane(lm,lh) reg r = O[q = (r&3)+8*(r>>2)+4*lh][dh = lm]; w12 = q (A), 32+q (B)
  #pragma unroll
  for (int r = 0; r < 16; r++){
    int q_l = (r&3) + 8*(r>>2) + 4*lh;
    float a = oA[r] * __shfl(invA, q_l, 64);
    float b = oB[r] * __shfl(invB, q_l, 64);
    atomicAdd(&abar_s[q_l*32 + lm], a);
    atomicAdd(&abar_s[(32 + q_l)*32 + lm], b);
  }
  __syncthreads();
  u16* ob = abar + (size_t)(bl*64)*128 + h*32;
  for (int idx = tid; idx < 2048; idx += 384){
    int w12 = idx >> 5, dh = idx & 31;
    *(__bf16*)&ob[(size_t)w12*128 + dh] = (__bf16)abar_s[idx];
  }
}

// ---------------------------------------------------------------- k_out
__global__ __launch_bounds__(256) void k_out(
    const u16* __restrict__ abar, const u16* __restrict__ wpT,
    const float* __restrict__ bp, const float* __restrict__ skip,
    float* __restrict__ out)
{
  __shared__ alignas(16) u16 Als[64*136];
  int tid = threadIdx.x;
  int R0 = blockIdx.x * 64;
  #pragma unroll
  for (int i = 0; i < 4; i++){
    int c = tid + i*256;
    int row = c >> 4, part = c & 15;
    *(u16x8*)&Als[row*136 + part*8] = *(const u16x8*)(abar + (size_t)(R0+row)*128 + part*8);
  }
  __syncthreads();
  int wave = tid >> 6, lane = tid & 63, lm = lane & 31, lh = lane >> 5;
  bf16x8 bfr[8];
  const u16* wrow = wpT + (32*wave + lm)*128 + lh*8;
  #pragma unroll
  for (int ks = 0; ks < 8; ks++) bfr[ks] = *(const bf16x8*)(wrow + ks*16);
  f32x16 acc0, acc1;
  #pragma unroll
  for (int r = 0; r < 16; r++){ acc0[r]=0.f; acc1[r]=0.f; }
  #pragma unroll
  for (int ks = 0; ks < 8; ks++){
    bf16x8 a0 = *(const bf16x8*)&Als[lm*136      + ks*16 + lh*8];
    bf16x8 a1 = *(const bf16x8*)&Als[(32+lm)*136 + ks*16 + lh*8];
    acc0 = mfma_bf16(a0, bfr[ks], acc0);
    acc1 = mfma_bf16(a1, bfr[ks], acc1);
  }
  float bias = bp[32*wave + lm];
  #pragma unroll
  for (int r = 0; r < 16; r++){
    int row0 = (r&3) + 8*(r>>2) + 4*lh;
    size_t f0 = (size_t)(R0 + row0)*128 + 32*wave + lm;
    out[f0] = acc0[r] + bias + skip[f0];
    size_t f1 = (size_t)(R0 + 32 + row0)*128 + 32*wave + lm;
    out[f1] = acc1[r] + bias + skip[f1];
  }
}

// ---------------------------------------------------------------- launch
extern "C" void kernel_launch(void* const* d_in, const int* in_sizes, int n_in,
                              void* d_out, int out_size, void* d_ws, size_t ws_size,
                              hipStream_t stream)
{
  const float* q    = (const float*)d_in[0];
  const float* k    = (const float*)d_in[1];
  const float* v    = (const float*)d_in[2];
  const float* skip = (const float*)d_in[3];
  const float* gq   = (const float*)d_in[4];
  const float* betq = (const float*)d_in[5];
  const float* gk   = (const float*)d_in[6];
  const float* betk = (const float*)d_in[7];
  const float* gv   = (const float*)d_in[8];
  const float* betv = (const float*)d_in[9];
  const float* wq   = (const float*)d_in[10];
  const float* bq   = (const float*)d_in[11];
  const float* wk   = (const float*)d_in[12];
  const float* bk   = (const float*)d_in[13];
  const float* wv   = (const float*)d_in[14];
  const float* bv   = (const float*)d_in[15];
  const float* wp   = (const float*)d_in[16];
  const float* bp   = (const float*)d_in[17];
  float* out = (float*)d_out;

  char* ws = (char*)d_ws;
  u16* wqT = (u16*)ws;                 // 16384 u16 each
  u16* wkT = wqT + 16384;
  u16* wvT = wkT + 16384;
  u16* wpT = wvT + 16384;
  float* bq2 = (float*)(ws + 131072);  // 128 f32 each
  float* bk2 = bq2 + 128;
  float* bv2 = bk2 + 128;
  float* uq2 = bv2 + 128;
  float* uk2 = uq2 + 128;
  float* uv2 = uk2 + 128;
  u16* qh = (u16*)(ws + 134144);       // [128][4][384][32] bf16 = 12.58 MB each
  u16* kh = qh + 6291456;
  u16* vh = kh + 6291456;
  u16* abar = vh + 6291456;            // [8192][128] bf16 = 2 MB

  k_prep  <<<4,    512, 0, stream>>>(wq,bq,gq,betq, wk,bk,gk,betk, wv,bv,gv,betv, wp,
                                     wqT,wkT,wvT,wpT, bq2,bk2,bv2, uq2,uk2,uv2);
  k_lnproj<<<2304, 256, 0, stream>>>(q,k,v, wqT,wkT,wvT, bq2,bk2,bv2, uq2,uk2,uv2, qh,kh,vh);
  k_attn  <<<512,  384, 0, stream>>>(qh,kh,vh, abar);
  k_out   <<<128,  256, 0, stream>>>(abar, wpT, bp, skip, out);
}